// Round 3
// baseline (1042.213 us; speedup 1.0000x reference)
//
#include <hip/hip_runtime.h>
#include <math.h>

// Problem constants
#define KC 1024
#define DD 256
#define NT 65536
#define MARGIN 2.0e-4f
#define HCAP 16384

// ws layout (in floats)
#define W_COUNTS 0
#define W_DW     1024
#define W_LOSS   263168
#define W_HCNT   263169
#define W_CNORM  263172      // 16B aligned
#define W_HLIST  264196
#define W_CCAT   280580      // 16B aligned (280580*4 % 16 == 0)
#define W_IDX    542724      // int idxw[NT]
// total: 542724 + 65536 = 608260 floats (~2.43 MB)

typedef _Float16 h8 __attribute__((ext_vector_type(8)));
typedef _Float16 h4 __attribute__((ext_vector_type(4)));
typedef float f32x4 __attribute__((ext_vector_type(4)));

__device__ __forceinline__ void gl_lds16(const _Float16* g, _Float16* l) {
    __builtin_amdgcn_global_load_lds(
        (const __attribute__((address_space(1))) unsigned int*)g,
        (__attribute__((address_space(3))) unsigned int*)l, 16, 0, 0);
}

// merge running top-2 triple (v1,i1,v2) with incoming (b1,bi,b2)
__device__ __forceinline__ void merge2(float& v1, float& i1, float& v2,
                                       float b1, float bi, float b2) {
    if (b1 < v1) { v2 = fminf(v1, b2); v1 = b1; i1 = bi; }
    else         { v2 = fminf(v2, b1); }
}

// ---------------------------------------------------------------- prepx ----
__global__ __launch_bounds__(256) void vq_prepx(const float* __restrict__ X,
                                                _Float16* __restrict__ Xcat) {
    int gid = blockIdx.x * 256 + threadIdx.x;        // 4,194,304 float4s
    float4 v = reinterpret_cast<const float4*>(X)[gid];
    int n = gid >> 6, d = (gid & 63) << 2;
    h4 hi, lo;
    hi[0] = (_Float16)v.x; lo[0] = (_Float16)(v.x - (float)hi[0]);
    hi[1] = (_Float16)v.y; lo[1] = (_Float16)(v.y - (float)hi[1]);
    hi[2] = (_Float16)v.z; lo[2] = (_Float16)(v.z - (float)hi[2]);
    hi[3] = (_Float16)v.w; lo[3] = (_Float16)(v.w - (float)hi[3]);
    *(h4*)(Xcat + (size_t)n * 512 + d)       = hi;
    *(h4*)(Xcat + (size_t)n * 512 + 256 + d) = lo;
}

// ---------------------------------------------------------------- prep ----
// Ccat = codebook * 2^14 split into fp16 hi|lo; cnorm = EXACT round-1 code.
__global__ __launch_bounds__(64) void vq_prep(const float* __restrict__ cb,
                                              _Float16* __restrict__ Ccat,
                                              float* __restrict__ cnorm) {
    const int k = blockIdx.x;
    const int l = threadIdx.x;
    float4 v = reinterpret_cast<const float4*>(cb)[k * 64 + l];
    float sx = v.x * 16384.0f, sy = v.y * 16384.0f,
          sz = v.z * 16384.0f, sw = v.w * 16384.0f;
    h4 hi, lo;
    hi[0] = (_Float16)sx; lo[0] = (_Float16)(sx - (float)hi[0]);
    hi[1] = (_Float16)sy; lo[1] = (_Float16)(sy - (float)hi[1]);
    hi[2] = (_Float16)sz; lo[2] = (_Float16)(sz - (float)hi[2]);
    hi[3] = (_Float16)sw; lo[3] = (_Float16)(sw - (float)hi[3]);
    *(h4*)(Ccat + (size_t)k * 512 + 4 * l)       = hi;
    *(h4*)(Ccat + (size_t)k * 512 + 256 + 4 * l) = lo;
    float s = v.x * v.x + v.y * v.y + v.z * v.z + v.w * v.w;
    #pragma unroll
    for (int off = 32; off; off >>= 1) s += __shfl_down(s, off, 64);
    if (l == 0) cnorm[k] = s;
}

// --------------------------------------------------------------- screen ----
__global__ __launch_bounds__(256) void vq_screen(
        const _Float16* __restrict__ Xcat, const _Float16* __restrict__ Ccat,
        const float* __restrict__ cnorm, float* __restrict__ counts,
        int* __restrict__ idxw, float* __restrict__ idxf,
        int* __restrict__ hardCnt, int* __restrict__ hardList) {
    __shared__ _Float16 As[8192];        // 128 x 64 halves, XOR-swizzled
    __shared__ _Float16 Bs[8192];
    __shared__ float wbuf[2][128][3];
    __shared__ float run[128][3];
    const int t = threadIdx.x;
    const int lane = t & 63, w = t >> 6;
    const int wm0 = (w & 1) * 64, wn0 = (w >> 1) * 64;
    const int row0 = blockIdx.x * 128;
    if (t < 128) { run[t][0] = 3.4e38f; run[t][1] = 0.f; run[t][2] = 3.4e38f; }

    int sA[4], mA[4], kgA[4];
    #pragma unroll
    for (int c = 0; c < 4; ++c) {
        int s = (w * 4 + c) * 64 + lane;
        sA[c] = s; mA[c] = s >> 3;
        kgA[c] = (((s & 7) ^ ((s >> 3) & 7)) << 3);
    }

    for (int ct = 0; ct < 8; ++ct) {
        const int cb0 = ct * 128;
        f32x4 acc[4][4];
        #pragma unroll
        for (int i = 0; i < 4; ++i)
            #pragma unroll
            for (int j = 0; j < 4; ++j) acc[i][j] = {0.f, 0.f, 0.f, 0.f};

        for (int ch = 0; ch < 12; ++ch) {
            const int seg = ch >> 2, dk = ch & 3;
            const int kA = (seg == 2 ? 256 : 0) + dk * 64;
            const int kB = (seg == 1 ? 256 : 0) + dk * 64;
            __syncthreads();
            #pragma unroll
            for (int c = 0; c < 4; ++c) {
                gl_lds16(Xcat + (size_t)(row0 + mA[c]) * 512 + kA + kgA[c], As + sA[c] * 8);
                gl_lds16(Ccat + (size_t)(cb0  + mA[c]) * 512 + kB + kgA[c], Bs + sA[c] * 8);
            }
            __syncthreads();
            #pragma unroll
            for (int ks = 0; ks < 2; ++ks) {
                h8 av[4], bv[4];
                const int kg = ks * 4 + (lane >> 4);
                #pragma unroll
                for (int f = 0; f < 4; ++f) {
                    int ma = wm0 + f * 16 + (lane & 15);
                    av[f] = *(const h8*)(As + ma * 64 + ((kg ^ (ma & 7)) << 3));
                    int nb = wn0 + f * 16 + (lane & 15);
                    bv[f] = *(const h8*)(Bs + nb * 64 + ((kg ^ (nb & 7)) << 3));
                }
                #pragma unroll
                for (int i = 0; i < 4; ++i)
                    #pragma unroll
                    for (int j = 0; j < 4; ++j)
                        acc[i][j] = __builtin_amdgcn_mfma_f32_16x16x32_f16(
                            av[i], bv[j], acc[i][j], 0, 0, 0);
            }
        }
        // epilogue: q = cn - acc*2^-13, per-row top2 across tile
        float cnv[4]; float gnf[4];
        #pragma unroll
        for (int fj = 0; fj < 4; ++fj) {
            int gn = cb0 + wn0 + fj * 16 + (lane & 15);
            gnf[fj] = (float)gn; cnv[fj] = cnorm[gn];
        }
        #pragma unroll
        for (int fi = 0; fi < 4; ++fi) {
            #pragma unroll
            for (int r = 0; r < 4; ++r) {
                float v1 = 3.4e38f, i1 = 0.f, v2 = 3.4e38f;
                #pragma unroll
                for (int fj = 0; fj < 4; ++fj) {
                    float q = fmaf(acc[fi][fj][r], -1.220703125e-4f, cnv[fj]);
                    merge2(v1, i1, v2, q, gnf[fj], 3.4e38f);
                }
                #pragma unroll
                for (int msk = 1; msk <= 8; msk <<= 1) {
                    float b1 = __shfl_xor(v1, msk, 64);
                    float bi = __shfl_xor(i1, msk, 64);
                    float b2 = __shfl_xor(v2, msk, 64);
                    merge2(v1, i1, v2, b1, bi, b2);
                }
                if ((lane & 15) == 0) {
                    int row = wm0 + fi * 16 + (lane >> 4) * 4 + r;
                    wbuf[w >> 1][row][0] = v1;
                    wbuf[w >> 1][row][1] = i1;
                    wbuf[w >> 1][row][2] = v2;
                }
            }
        }
        __syncthreads();
        if (t < 128) {
            float v1 = run[t][0], i1 = run[t][1], v2 = run[t][2];
            merge2(v1, i1, v2, wbuf[0][t][0], wbuf[0][t][1], wbuf[0][t][2]);
            merge2(v1, i1, v2, wbuf[1][t][0], wbuf[1][t][1], wbuf[1][t][2]);
            run[t][0] = v1; run[t][1] = i1; run[t][2] = v2;
        }
    }
    if (t < 128) {
        float v1 = run[t][0], fi1 = run[t][1], v2 = run[t][2];
        int i1 = (int)fi1;
        int n = row0 + t;
        idxf[n] = fi1; idxw[n] = i1;
        if (v2 - v1 > MARGIN) {
            unsafeAtomicAdd(&counts[i1], 1.0f);
        } else {
            int p = atomicAdd(hardCnt, 1);
            if (p < HCAP) hardList[p] = n;
            else unsafeAtomicAdd(&counts[i1], 1.0f);
        }
    }
}

// ---------------------------------------------------------------- exact ----
__global__ __launch_bounds__(256) void vq_exact(
        const float* __restrict__ X, const float* __restrict__ CB,
        const float* __restrict__ cnorm, const int* __restrict__ hardCnt,
        const int* __restrict__ hardList, float* __restrict__ counts,
        int* __restrict__ idxw, float* __restrict__ idxf) {
    __shared__ float xs[8][256];
    __shared__ float xnv[8];
    __shared__ float cbs[64][256];
    __shared__ int   toks[8];
    __shared__ float red[8][32][2];
    const int cnt = min(*hardCnt, HCAP);
    const int g0 = blockIdx.x * 8;
    if (g0 >= cnt) return;
    const int t = threadIdx.x;
    const int ntk = min(8, cnt - g0);
    if (t < 8) toks[t] = hardList[g0 + (t < ntk ? t : 0)];
    __syncthreads();
    {
        int tk = t >> 5, sl = t & 31;
        const float4* src = (const float4*)(X + (size_t)toks[tk] * 256);
        *(float4*)&xs[tk][sl * 8]     = src[sl * 2];
        *(float4*)&xs[tk][sl * 8 + 4] = src[sl * 2 + 1];
    }
    __syncthreads();
    if (t < 8) {
        #pragma clang fp contract(off)
        float tot = 0.f;
        #pragma unroll
        for (int h = 0; h < 2; ++h) {
            float r[8];
            #pragma unroll
            for (int j = 0; j < 8; ++j) { float a = xs[t][h * 128 + j]; float p = a * a; r[j] = p; }
            for (int i = 1; i < 16; ++i) {
                #pragma unroll
                for (int j = 0; j < 8; ++j) { float a = xs[t][h * 128 + i * 8 + j]; float p = a * a; r[j] = r[j] + p; }
            }
            float s = ((r[0] + r[1]) + (r[2] + r[3])) + ((r[4] + r[5]) + (r[6] + r[7]));
            tot = tot + s;
        }
        xnv[t] = tot;
    }
    float bS = 3.4e38f; float bI = 0.f;
    const int tk = t >> 5, tc = t & 31;
    for (int ch = 0; ch < 16; ++ch) {
        __syncthreads();
        {
            const float4* s4 = (const float4*)(CB + (size_t)ch * 64 * 256);
            float4* dst = (float4*)&cbs[0][0];
            #pragma unroll
            for (int u = 0; u < 16; ++u) dst[u * 256 + t] = s4[u * 256 + t];
        }
        __syncthreads();
        {
            #pragma clang fp contract(off)
            float a0 = 0.f, a1 = 0.f;
            const float* xr = xs[tk];
            const float* c0 = cbs[tc];
            const float* c1 = cbs[tc + 32];
            for (int d = 0; d < 256; ++d) {
                float xv = xr[d];
                a0 = fmaf(xv, c0[d], a0);
                a1 = fmaf(xv, c1[d], a1);
            }
            int gc0 = ch * 64 + tc, gc1 = gc0 + 32;
            float t1a = xnv[tk] + cnorm[gc0];
            float t2a = 2.0f * a0;
            float s0 = t1a - t2a;
            float t1b = xnv[tk] + cnorm[gc1];
            float t2b = 2.0f * a1;
            float s1 = t1b - t2b;
            if (s0 < bS) { bS = s0; bI = (float)gc0; }
            if (s1 < bS) { bS = s1; bI = (float)gc1; }
        }
    }
    __syncthreads();
    red[tk][tc][0] = bS; red[tk][tc][1] = bI;
    __syncthreads();
    if (t < ntk) {
        float v = 3.4e38f, bi = 0.f;
        for (int c = 0; c < 32; ++c) {
            float s = red[t][c][0], ii = red[t][c][1];
            if (s < v || (s == v && ii < bi)) { v = s; bi = ii; }
        }
        int n = toks[t];
        idxf[n] = bi; idxw[n] = (int)bi;
        unsafeAtomicAdd(&counts[(int)bi], 1.0f);
    }
}

// -------------------------------------------------------------- gather ----
__global__ __launch_bounds__(256) void vq_gather(const float* __restrict__ X,
                                                 const float* __restrict__ CB,
                                                 const int* __restrict__ idxw,
                                                 float* __restrict__ out0,
                                                 float* __restrict__ dw,
                                                 float* __restrict__ loss) {
    const int t    = threadIdx.x;
    const int wave = (blockIdx.x * 256 + t) >> 6;
    const int lane = t & 63;
    const float4* X4 = reinterpret_cast<const float4*>(X);
    const float4* C4 = reinterpret_cast<const float4*>(CB);
    float4* O4 = reinterpret_cast<float4*>(out0);
    float lsum = 0.f;
    for (int r = 0; r < 64; ++r) {
        const int n = wave * 64 + r;
        const int idx = idxw[n];
        float4 x = X4[n * 64 + lane];
        float4 c = C4[idx * 64 + lane];
        float d0 = c.x - x.x, d1 = c.y - x.y, d2 = c.z - x.z, d3 = c.w - x.w;
        float4 q;
        q.x = x.x + d0; q.y = x.y + d1; q.z = x.z + d2; q.w = x.w + d3;
        O4[n * 64 + lane] = q;
        lsum += d0 * d0 + d1 * d1 + d2 * d2 + d3 * d3;
        int base = idx * 256 + lane * 4;
        unsafeAtomicAdd(&dw[base + 0], x.x);
        unsafeAtomicAdd(&dw[base + 1], x.y);
        unsafeAtomicAdd(&dw[base + 2], x.z);
        unsafeAtomicAdd(&dw[base + 3], x.w);
    }
    #pragma unroll
    for (int off = 32; off; off >>= 1) lsum += __shfl_down(lsum, off, 64);
    if (lane == 0) unsafeAtomicAdd(loss, lsum);
}

// ---------------------------------------------------------- finalize 1 ----
__global__ void vq_fin1(const float* __restrict__ counts,
                        const float* __restrict__ ecs,
                        const float* __restrict__ loss,
                        float* __restrict__ out1, float* __restrict__ out3,
                        float* __restrict__ out4) {
    __shared__ float sd[1024];
    const int t = threadIdx.x;
    float c   = counts[t];
    float pre = 0.99f * ecs[t] + 0.01f * c;
    sd[t] = pre; __syncthreads();
    for (int off = 512; off; off >>= 1) { if (t < off) sd[t] += sd[t + off]; __syncthreads(); }
    float n_total = sd[0];
    __syncthreads();
    float avg = c * (1.0f / 65536.0f);
    float ent = avg * logf(avg + 1e-10f);
    sd[t] = ent; __syncthreads();
    for (int off = 512; off; off >>= 1) { if (t < off) sd[t] += sd[t + off]; __syncthreads(); }
    float entsum = sd[0];
    float ncs = (pre + 1e-5f) / (n_total + 1024.0f * 1e-5f) * n_total;
    out4[t] = ncs;
    if (t == 0) {
        out1[0] = 0.25f * (loss[0] / 16777216.0f);
        out3[0] = expf(-entsum);
    }
}

// ---------------------------------------------------------- finalize 2 ----
__global__ __launch_bounds__(256) void vq_fin2(const float* __restrict__ emw,
                                               const float* __restrict__ dwv,
                                               const float* __restrict__ ncs,
                                               float* __restrict__ out5,
                                               float* __restrict__ out6) {
    int i = blockIdx.x * 256 + threadIdx.x;
    float e = 0.99f * emw[i] + 0.01f * dwv[i];
    out5[i] = e;
    out6[i] = e / ncs[i >> 8];
}

// ---------------------------------------------------------------- launch --
extern "C" void kernel_launch(void* const* d_in, const int* in_sizes, int n_in,
                              void* d_out, int out_size, void* d_ws, size_t ws_size,
                              hipStream_t stream) {
    const float* X   = (const float*)d_in[0];
    const float* CB  = (const float*)d_in[1];
    const float* ECS = (const float*)d_in[2];
    const float* EMW = (const float*)d_in[3];

    float* out0 = (float*)d_out;
    float* out1 = out0 + (size_t)NT * DD;
    float* out2 = out1 + 1;
    float* out3 = out2 + NT;
    float* out4 = out3 + 1;
    float* out5 = out4 + KC;
    float* out6 = out5 + (size_t)KC * DD;

    float* ws       = (float*)d_ws;
    float* counts   = ws + W_COUNTS;
    float* dw       = ws + W_DW;
    float* loss     = ws + W_LOSS;
    int*   hardCnt  = (int*)(ws + W_HCNT);
    float* cnorm    = ws + W_CNORM;
    int*   hardList = (int*)(ws + W_HLIST);
    _Float16* Ccat  = (_Float16*)(ws + W_CCAT);
    int*   idxw     = (int*)(ws + W_IDX);

    // Xcat (64 MB halves) aliases out0: read in screen, out0 written later.
    _Float16* Xcat = (_Float16*)d_out;

    (void)hipMemsetAsync(ws, 0, (size_t)(W_LOSS + 2) * sizeof(float), stream);

    vq_prepx<<<NT * DD / 4 / 256, 256, 0, stream>>>(X, Xcat);
    vq_prep<<<KC, 64, 0, stream>>>(CB, Ccat, cnorm);
    vq_screen<<<NT / 128, 256, 0, stream>>>(Xcat, Ccat, cnorm, counts, idxw, out2,
                                            hardCnt, hardList);
    vq_exact<<<HCAP / 8, 256, 0, stream>>>(X, CB, cnorm, hardCnt, hardList,
                                           counts, idxw, out2);
    vq_gather<<<256, 256, 0, stream>>>(X, CB, idxw, out0, dw, loss);
    vq_fin1<<<1, 1024, 0, stream>>>(counts, ECS, loss, out1, out3, out4);
    vq_fin2<<<KC * DD / 256, 256, 0, stream>>>(EMW, dw, out4, out5, out6);
}

// Round 4
// 677.575 us; speedup vs baseline: 1.5382x; 1.5382x over previous
//
#include <hip/hip_runtime.h>
#include <math.h>

// Problem constants
#define KC 1024
#define DD 256
#define NT 65536
#define MARGIN 2.0e-4f
#define HCAP 16384

// ws layout (in floats)
#define W_COUNTS 0
#define W_DW     1024
#define W_LOSS   263168
#define W_HCNT   263169
#define W_CNORM  263172      // 16B aligned
#define W_HLIST  264196
#define W_CCAT   280580      // 16B aligned
#define W_IDX    542724      // int idxw[NT]
#define W_CBT    608260      // float cbT[256*1024], d-major; 16B aligned
// total: 608260 + 262144 = 870404 floats (~3.48 MB)

typedef _Float16 h8 __attribute__((ext_vector_type(8)));
typedef _Float16 h4 __attribute__((ext_vector_type(4)));
typedef float f32x4 __attribute__((ext_vector_type(4)));

__device__ __forceinline__ void gl_lds16(const _Float16* g, _Float16* l) {
    __builtin_amdgcn_global_load_lds(
        (const __attribute__((address_space(1))) unsigned int*)g,
        (__attribute__((address_space(3))) unsigned int*)l, 16, 0, 0);
}

// merge running top-2 triple (v1,i1,v2) with incoming (b1,bi,b2)
__device__ __forceinline__ void merge2(float& v1, float& i1, float& v2,
                                       float b1, float bi, float b2) {
    if (b1 < v1) { v2 = fminf(v1, b2); v1 = b1; i1 = bi; }
    else         { v2 = fminf(v2, b1); }
}

// ---------------------------------------------------------------- prepx ----
__global__ __launch_bounds__(256) void vq_prepx(const float* __restrict__ X,
                                                _Float16* __restrict__ Xcat) {
    int gid = blockIdx.x * 256 + threadIdx.x;
    float4 v = reinterpret_cast<const float4*>(X)[gid];
    int n = gid >> 6, d = (gid & 63) << 2;
    h4 hi, lo;
    hi[0] = (_Float16)v.x; lo[0] = (_Float16)(v.x - (float)hi[0]);
    hi[1] = (_Float16)v.y; lo[1] = (_Float16)(v.y - (float)hi[1]);
    hi[2] = (_Float16)v.z; lo[2] = (_Float16)(v.z - (float)hi[2]);
    hi[3] = (_Float16)v.w; lo[3] = (_Float16)(v.w - (float)hi[3]);
    *(h4*)(Xcat + (size_t)n * 512 + d)       = hi;
    *(h4*)(Xcat + (size_t)n * 512 + 256 + d) = lo;
}

// ---------------------------------------------------------------- prep ----
// Ccat = codebook * 2^14 split fp16 hi|lo; cbT = d-major transpose;
// cnorm = EXACT round-1 computation.
__global__ __launch_bounds__(64) void vq_prep(const float* __restrict__ cb,
                                              _Float16* __restrict__ Ccat,
                                              float* __restrict__ cnorm,
                                              float* __restrict__ cbT) {
    const int k = blockIdx.x;
    const int l = threadIdx.x;
    float4 v = reinterpret_cast<const float4*>(cb)[k * 64 + l];
    cbT[(4 * l + 0) * KC + k] = v.x;
    cbT[(4 * l + 1) * KC + k] = v.y;
    cbT[(4 * l + 2) * KC + k] = v.z;
    cbT[(4 * l + 3) * KC + k] = v.w;
    float sx = v.x * 16384.0f, sy = v.y * 16384.0f,
          sz = v.z * 16384.0f, sw = v.w * 16384.0f;
    h4 hi, lo;
    hi[0] = (_Float16)sx; lo[0] = (_Float16)(sx - (float)hi[0]);
    hi[1] = (_Float16)sy; lo[1] = (_Float16)(sy - (float)hi[1]);
    hi[2] = (_Float16)sz; lo[2] = (_Float16)(sz - (float)hi[2]);
    hi[3] = (_Float16)sw; lo[3] = (_Float16)(sw - (float)hi[3]);
    *(h4*)(Ccat + (size_t)k * 512 + 4 * l)       = hi;
    *(h4*)(Ccat + (size_t)k * 512 + 256 + 4 * l) = lo;
    float s = v.x * v.x + v.y * v.y + v.z * v.z + v.w * v.w;
    #pragma unroll
    for (int off = 32; off; off >>= 1) s += __shfl_down(s, off, 64);
    if (l == 0) cnorm[k] = s;
}

// --------------------------------------------------------------- screen ----
__global__ __launch_bounds__(256) void vq_screen(
        const _Float16* __restrict__ Xcat, const _Float16* __restrict__ Ccat,
        const float* __restrict__ cnorm, float* __restrict__ counts,
        int* __restrict__ idxw, float* __restrict__ idxf,
        int* __restrict__ hardCnt, int* __restrict__ hardList) {
    __shared__ _Float16 As[8192];        // 128 x 64 halves, XOR-swizzled
    __shared__ _Float16 Bs[8192];
    __shared__ float wbuf[2][128][3];
    __shared__ float run[128][3];
    const int t = threadIdx.x;
    const int lane = t & 63, w = t >> 6;
    const int wm0 = (w & 1) * 64, wn0 = (w >> 1) * 64;
    const int row0 = blockIdx.x * 128;
    if (t < 128) { run[t][0] = 3.4e38f; run[t][1] = 0.f; run[t][2] = 3.4e38f; }

    int sA[4], mA[4], kgA[4];
    #pragma unroll
    for (int c = 0; c < 4; ++c) {
        int s = (w * 4 + c) * 64 + lane;
        sA[c] = s; mA[c] = s >> 3;
        kgA[c] = (((s & 7) ^ ((s >> 3) & 7)) << 3);
    }

    for (int ct = 0; ct < 8; ++ct) {
        const int cb0 = ct * 128;
        f32x4 acc[4][4];
        #pragma unroll
        for (int i = 0; i < 4; ++i)
            #pragma unroll
            for (int j = 0; j < 4; ++j) acc[i][j] = {0.f, 0.f, 0.f, 0.f};

        for (int ch = 0; ch < 12; ++ch) {
            const int seg = ch >> 2, dk = ch & 3;
            const int kA = (seg == 2 ? 256 : 0) + dk * 64;
            const int kB = (seg == 1 ? 256 : 0) + dk * 64;
            __syncthreads();
            #pragma unroll
            for (int c = 0; c < 4; ++c) {
                gl_lds16(Xcat + (size_t)(row0 + mA[c]) * 512 + kA + kgA[c], As + sA[c] * 8);
                gl_lds16(Ccat + (size_t)(cb0  + mA[c]) * 512 + kB + kgA[c], Bs + sA[c] * 8);
            }
            __syncthreads();
            #pragma unroll
            for (int ks = 0; ks < 2; ++ks) {
                h8 av[4], bv[4];
                const int kg = ks * 4 + (lane >> 4);
                #pragma unroll
                for (int f = 0; f < 4; ++f) {
                    int ma = wm0 + f * 16 + (lane & 15);
                    av[f] = *(const h8*)(As + ma * 64 + ((kg ^ (ma & 7)) << 3));
                    int nb = wn0 + f * 16 + (lane & 15);
                    bv[f] = *(const h8*)(Bs + nb * 64 + ((kg ^ (nb & 7)) << 3));
                }
                #pragma unroll
                for (int i = 0; i < 4; ++i)
                    #pragma unroll
                    for (int j = 0; j < 4; ++j)
                        acc[i][j] = __builtin_amdgcn_mfma_f32_16x16x32_f16(
                            av[i], bv[j], acc[i][j], 0, 0, 0);
            }
        }
        // epilogue: q = cn - acc*2^-13, per-row top2 across tile
        float cnv[4]; float gnf[4];
        #pragma unroll
        for (int fj = 0; fj < 4; ++fj) {
            int gn = cb0 + wn0 + fj * 16 + (lane & 15);
            gnf[fj] = (float)gn; cnv[fj] = cnorm[gn];
        }
        #pragma unroll
        for (int fi = 0; fi < 4; ++fi) {
            #pragma unroll
            for (int r = 0; r < 4; ++r) {
                float v1 = 3.4e38f, i1 = 0.f, v2 = 3.4e38f;
                #pragma unroll
                for (int fj = 0; fj < 4; ++fj) {
                    float q = fmaf(acc[fi][fj][r], -1.220703125e-4f, cnv[fj]);
                    merge2(v1, i1, v2, q, gnf[fj], 3.4e38f);
                }
                #pragma unroll
                for (int msk = 1; msk <= 8; msk <<= 1) {
                    float b1 = __shfl_xor(v1, msk, 64);
                    float bi = __shfl_xor(i1, msk, 64);
                    float b2 = __shfl_xor(v2, msk, 64);
                    merge2(v1, i1, v2, b1, bi, b2);
                }
                if ((lane & 15) == 0) {
                    int row = wm0 + fi * 16 + (lane >> 4) * 4 + r;
                    wbuf[w >> 1][row][0] = v1;
                    wbuf[w >> 1][row][1] = i1;
                    wbuf[w >> 1][row][2] = v2;
                }
            }
        }
        __syncthreads();
        if (t < 128) {
            float v1 = run[t][0], i1 = run[t][1], v2 = run[t][2];
            merge2(v1, i1, v2, wbuf[0][t][0], wbuf[0][t][1], wbuf[0][t][2]);
            merge2(v1, i1, v2, wbuf[1][t][0], wbuf[1][t][1], wbuf[1][t][2]);
            run[t][0] = v1; run[t][1] = i1; run[t][2] = v2;
        }
    }
    if (t < 128) {
        float v1 = run[t][0], fi1 = run[t][1], v2 = run[t][2];
        int i1 = (int)fi1;
        int n = row0 + t;
        idxf[n] = fi1; idxw[n] = i1;
        if (v2 - v1 > MARGIN) {
            unsafeAtomicAdd(&counts[i1], 1.0f);
        } else {
            int p = atomicAdd(hardCnt, 1);
            if (p < HCAP) hardList[p] = n;
            else unsafeAtomicAdd(&counts[i1], 1.0f);
        }
    }
}

// ---------------------------------------------------------------- exact ----
// Full 1024-code exact rescan, conflict-free layout: codebook chunk staged
// d-major (cbs[d*64+c]) from pre-transposed cbT. Lane reads cbs[d*64+tc]:
// 32 consecutive banks, 2-way broadcast across tk halves => conflict-free.
// fmaf chain order per (token,code) is IDENTICAL to the proven round-1 chain.
__global__ __launch_bounds__(256) void vq_exact(
        const float* __restrict__ X, const float* __restrict__ cbT,
        const float* __restrict__ cnorm, const int* __restrict__ hardCnt,
        const int* __restrict__ hardList, float* __restrict__ counts,
        int* __restrict__ idxw, float* __restrict__ idxf) {
    __shared__ float xs[8][256];
    __shared__ float xnv[8];
    __shared__ float cbs[64 * 256];      // d-major: cbs[d*64 + c], 64 KB
    __shared__ int   toks[8];
    __shared__ float red[8][32][2];
    const int cnt = min(*hardCnt, HCAP);
    const int g0 = blockIdx.x * 8;
    if (g0 >= cnt) return;
    const int t = threadIdx.x;
    const int ntk = min(8, cnt - g0);
    if (t < 8) toks[t] = hardList[g0 + (t < ntk ? t : 0)];
    __syncthreads();
    {
        int tk = t >> 5, sl = t & 31;
        const float4* src = (const float4*)(X + (size_t)toks[tk] * 256);
        *(float4*)&xs[tk][sl * 8]     = src[sl * 2];
        *(float4*)&xs[tk][sl * 8 + 4] = src[sl * 2 + 1];
    }
    __syncthreads();
    if (t < 8) {
        #pragma clang fp contract(off)
        float tot = 0.f;
        #pragma unroll
        for (int h = 0; h < 2; ++h) {
            float r[8];
            #pragma unroll
            for (int j = 0; j < 8; ++j) { float a = xs[t][h * 128 + j]; float p = a * a; r[j] = p; }
            for (int i = 1; i < 16; ++i) {
                #pragma unroll
                for (int j = 0; j < 8; ++j) { float a = xs[t][h * 128 + i * 8 + j]; float p = a * a; r[j] = r[j] + p; }
            }
            float s = ((r[0] + r[1]) + (r[2] + r[3])) + ((r[4] + r[5]) + (r[6] + r[7]));
            tot = tot + s;
        }
        xnv[t] = tot;
    }
    float bS = 3.4e38f; float bI = 0.f;
    const int tk = t >> 5, tc = t & 31;
    const float4* cbT4 = (const float4*)cbT;
    for (int ch = 0; ch < 16; ++ch) {
        __syncthreads();
        {   // stage 64 codes (d-major): cbs[d*16+c4 float4] = cbT[d][ch*64+4*c4..]
            #pragma unroll
            for (int u = 0; u < 16; ++u) {
                int fid = u * 256 + t;        // 0..4095
                int d = fid >> 4, c4 = fid & 15;
                ((float4*)cbs)[d * 16 + c4] = cbT4[(size_t)d * 256 + ch * 16 + c4];
            }
        }
        __syncthreads();
        {
            #pragma clang fp contract(off)
            float a0 = 0.f, a1 = 0.f;
            const float* xr = xs[tk];
            #pragma unroll 8
            for (int d4 = 0; d4 < 64; ++d4) {
                float4 xv = *(const float4*)(xr + 4 * d4);
                const float* cd = cbs + (4 * d4) * 64 + tc;
                a0 = fmaf(xv.x, cd[0],   a0);
                a1 = fmaf(xv.x, cd[32],  a1);
                a0 = fmaf(xv.y, cd[64],  a0);
                a1 = fmaf(xv.y, cd[96],  a1);
                a0 = fmaf(xv.z, cd[128], a0);
                a1 = fmaf(xv.z, cd[160], a1);
                a0 = fmaf(xv.w, cd[192], a0);
                a1 = fmaf(xv.w, cd[224], a1);
            }
            int gc0 = ch * 64 + tc, gc1 = gc0 + 32;
            float t1a = xnv[tk] + cnorm[gc0];
            float t2a = 2.0f * a0;
            float s0 = t1a - t2a;
            float t1b = xnv[tk] + cnorm[gc1];
            float t2b = 2.0f * a1;
            float s1 = t1b - t2b;
            if (s0 < bS) { bS = s0; bI = (float)gc0; }
            if (s1 < bS) { bS = s1; bI = (float)gc1; }
        }
    }
    __syncthreads();
    red[tk][tc][0] = bS; red[tk][tc][1] = bI;
    __syncthreads();
    if (t < ntk) {
        float v = 3.4e38f, bi = 0.f;
        for (int c = 0; c < 32; ++c) {
            float s = red[t][c][0], ii = red[t][c][1];
            if (s < v || (s == v && ii < bi)) { v = s; bi = ii; }
        }
        int n = toks[t];
        idxf[n] = bi; idxw[n] = (int)bi;
        unsafeAtomicAdd(&counts[(int)bi], 1.0f);
    }
}

// -------------------------------------------------------------- gather ----
__global__ __launch_bounds__(256) void vq_gather(const float* __restrict__ X,
                                                 const float* __restrict__ CB,
                                                 const int* __restrict__ idxw,
                                                 float* __restrict__ out0,
                                                 float* __restrict__ dw,
                                                 float* __restrict__ loss) {
    const int t    = threadIdx.x;
    const int wave = (blockIdx.x * 256 + t) >> 6;
    const int lane = t & 63;
    const float4* X4 = reinterpret_cast<const float4*>(X);
    const float4* C4 = reinterpret_cast<const float4*>(CB);
    float4* O4 = reinterpret_cast<float4*>(out0);
    float lsum = 0.f;
    for (int r = 0; r < 64; ++r) {
        const int n = wave * 64 + r;
        const int idx = idxw[n];
        float4 x = X4[n * 64 + lane];
        float4 c = C4[idx * 64 + lane];
        float d0 = c.x - x.x, d1 = c.y - x.y, d2 = c.z - x.z, d3 = c.w - x.w;
        float4 q;
        q.x = x.x + d0; q.y = x.y + d1; q.z = x.z + d2; q.w = x.w + d3;
        O4[n * 64 + lane] = q;
        lsum += d0 * d0 + d1 * d1 + d2 * d2 + d3 * d3;
        int base = idx * 256 + lane * 4;
        unsafeAtomicAdd(&dw[base + 0], x.x);
        unsafeAtomicAdd(&dw[base + 1], x.y);
        unsafeAtomicAdd(&dw[base + 2], x.z);
        unsafeAtomicAdd(&dw[base + 3], x.w);
    }
    #pragma unroll
    for (int off = 32; off; off >>= 1) lsum += __shfl_down(lsum, off, 64);
    if (lane == 0) unsafeAtomicAdd(loss, lsum);
}

// ---------------------------------------------------------- finalize 1 ----
__global__ void vq_fin1(const float* __restrict__ counts,
                        const float* __restrict__ ecs,
                        const float* __restrict__ loss,
                        float* __restrict__ out1, float* __restrict__ out3,
                        float* __restrict__ out4) {
    __shared__ float sd[1024];
    const int t = threadIdx.x;
    float c   = counts[t];
    float pre = 0.99f * ecs[t] + 0.01f * c;
    sd[t] = pre; __syncthreads();
    for (int off = 512; off; off >>= 1) { if (t < off) sd[t] += sd[t + off]; __syncthreads(); }
    float n_total = sd[0];
    __syncthreads();
    float avg = c * (1.0f / 65536.0f);
    float ent = avg * logf(avg + 1e-10f);
    sd[t] = ent; __syncthreads();
    for (int off = 512; off; off >>= 1) { if (t < off) sd[t] += sd[t + off]; __syncthreads(); }
    float entsum = sd[0];
    float ncs = (pre + 1e-5f) / (n_total + 1024.0f * 1e-5f) * n_total;
    out4[t] = ncs;
    if (t == 0) {
        out1[0] = 0.25f * (loss[0] / 16777216.0f);
        out3[0] = expf(-entsum);
    }
}

// ---------------------------------------------------------- finalize 2 ----
__global__ __launch_bounds__(256) void vq_fin2(const float* __restrict__ emw,
                                               const float* __restrict__ dwv,
                                               const float* __restrict__ ncs,
                                               float* __restrict__ out5,
                                               float* __restrict__ out6) {
    int i = blockIdx.x * 256 + threadIdx.x;
    float e = 0.99f * emw[i] + 0.01f * dwv[i];
    out5[i] = e;
    out6[i] = e / ncs[i >> 8];
}

// ---------------------------------------------------------------- launch --
extern "C" void kernel_launch(void* const* d_in, const int* in_sizes, int n_in,
                              void* d_out, int out_size, void* d_ws, size_t ws_size,
                              hipStream_t stream) {
    const float* X   = (const float*)d_in[0];
    const float* CB  = (const float*)d_in[1];
    const float* ECS = (const float*)d_in[2];
    const float* EMW = (const float*)d_in[3];

    float* out0 = (float*)d_out;
    float* out1 = out0 + (size_t)NT * DD;
    float* out2 = out1 + 1;
    float* out3 = out2 + NT;
    float* out4 = out3 + 1;
    float* out5 = out4 + KC;
    float* out6 = out5 + (size_t)KC * DD;

    float* ws       = (float*)d_ws;
    float* counts   = ws + W_COUNTS;
    float* dw       = ws + W_DW;
    float* loss     = ws + W_LOSS;
    int*   hardCnt  = (int*)(ws + W_HCNT);
    float* cnorm    = ws + W_CNORM;
    int*   hardList = (int*)(ws + W_HLIST);
    _Float16* Ccat  = (_Float16*)(ws + W_CCAT);
    int*   idxw     = (int*)(ws + W_IDX);
    float* cbT      = ws + W_CBT;

    // Xcat (67 MB halves) aliases out0: read in screen, out0 written later.
    _Float16* Xcat = (_Float16*)d_out;

    (void)hipMemsetAsync(ws, 0, (size_t)(W_LOSS + 2) * sizeof(float), stream);

    vq_prepx<<<NT * DD / 4 / 256, 256, 0, stream>>>(X, Xcat);
    vq_prep<<<KC, 64, 0, stream>>>(CB, Ccat, cnorm, cbT);
    vq_screen<<<NT / 128, 256, 0, stream>>>(Xcat, Ccat, cnorm, counts, idxw, out2,
                                            hardCnt, hardList);
    vq_exact<<<HCAP / 8, 256, 0, stream>>>(X, cbT, cnorm, hardCnt, hardList,
                                           counts, idxw, out2);
    vq_gather<<<256, 256, 0, stream>>>(X, CB, idxw, out0, dw, loss);
    vq_fin1<<<1, 1024, 0, stream>>>(counts, ECS, loss, out1, out3, out4);
    vq_fin2<<<KC * DD / 256, 256, 0, stream>>>(EMW, dw, out4, out5, out6);
}

// Round 5
// 508.789 us; speedup vs baseline: 2.0484x; 1.3317x over previous
//
#include <hip/hip_runtime.h>
#include <math.h>

// Problem constants
#define KC 1024
#define DD 256
#define NT 65536
#define MARGIN 2.0e-4f
#define HCAP 16384

// ws layout (in floats)
#define W_COUNTS 0            // float[1024]
#define W_LOSS   1024         // float[1]
#define W_HCNT   1025         // int[1]
#define W_CNORM  1028         // float[1024], 16B aligned
#define W_OFFS   2052         // int[1024]
#define W_CUR    3076         // int[1024]
#define W_HLIST  4100         // int[HCAP]
#define W_SORT   20484        // int[NT]
#define W_IDX    86020        // int[NT]
#define W_DWB    151556       // float[KC*DD]
#define W_CCAT   413700       // fp16[2*KC*DD] (16B aligned: 413700*4%16==0)
#define W_CBT    675844       // float[DD*KC]  (16B aligned)
// total: 937988 floats (~3.75 MB)

typedef _Float16 h8 __attribute__((ext_vector_type(8)));
typedef _Float16 h4 __attribute__((ext_vector_type(4)));
typedef float f32x4 __attribute__((ext_vector_type(4)));

__device__ __forceinline__ void gl_lds16(const _Float16* g, _Float16* l) {
    __builtin_amdgcn_global_load_lds(
        (const __attribute__((address_space(1))) unsigned int*)g,
        (__attribute__((address_space(3))) unsigned int*)l, 16, 0, 0);
}

__device__ __forceinline__ void merge2(float& v1, float& i1, float& v2,
                                       float b1, float bi, float b2) {
    if (b1 < v1) { v2 = fminf(v1, b2); v1 = b1; i1 = bi; }
    else         { v2 = fminf(v2, b1); }
}

// ---------------------------------------------------------------- prepx ----
__global__ __launch_bounds__(256) void vq_prepx(const float* __restrict__ X,
                                                _Float16* __restrict__ Xcat) {
    int gid = blockIdx.x * 256 + threadIdx.x;
    float4 v = reinterpret_cast<const float4*>(X)[gid];
    int n = gid >> 6, d = (gid & 63) << 2;
    h4 hi, lo;
    hi[0] = (_Float16)v.x; lo[0] = (_Float16)(v.x - (float)hi[0]);
    hi[1] = (_Float16)v.y; lo[1] = (_Float16)(v.y - (float)hi[1]);
    hi[2] = (_Float16)v.z; lo[2] = (_Float16)(v.z - (float)hi[2]);
    hi[3] = (_Float16)v.w; lo[3] = (_Float16)(v.w - (float)hi[3]);
    *(h4*)(Xcat + (size_t)n * 512 + d)       = hi;
    *(h4*)(Xcat + (size_t)n * 512 + 256 + d) = lo;
}

// ---------------------------------------------------------------- prep ----
__global__ __launch_bounds__(64) void vq_prep(const float* __restrict__ cb,
                                              _Float16* __restrict__ Ccat,
                                              float* __restrict__ cnorm,
                                              float* __restrict__ cbT) {
    const int k = blockIdx.x;
    const int l = threadIdx.x;
    float4 v = reinterpret_cast<const float4*>(cb)[k * 64 + l];
    cbT[(4 * l + 0) * KC + k] = v.x;
    cbT[(4 * l + 1) * KC + k] = v.y;
    cbT[(4 * l + 2) * KC + k] = v.z;
    cbT[(4 * l + 3) * KC + k] = v.w;
    float sx = v.x * 16384.0f, sy = v.y * 16384.0f,
          sz = v.z * 16384.0f, sw = v.w * 16384.0f;
    h4 hi, lo;
    hi[0] = (_Float16)sx; lo[0] = (_Float16)(sx - (float)hi[0]);
    hi[1] = (_Float16)sy; lo[1] = (_Float16)(sy - (float)hi[1]);
    hi[2] = (_Float16)sz; lo[2] = (_Float16)(sz - (float)hi[2]);
    hi[3] = (_Float16)sw; lo[3] = (_Float16)(sw - (float)hi[3]);
    *(h4*)(Ccat + (size_t)k * 512 + 4 * l)       = hi;
    *(h4*)(Ccat + (size_t)k * 512 + 256 + 4 * l) = lo;
    float s = v.x * v.x + v.y * v.y + v.z * v.z + v.w * v.w;
    #pragma unroll
    for (int off = 32; off; off >>= 1) s += __shfl_down(s, off, 64);
    if (l == 0) cnorm[k] = s;
}

// --------------------------------------------------------------- screen ----
__global__ __launch_bounds__(256) void vq_screen(
        const _Float16* __restrict__ Xcat, const _Float16* __restrict__ Ccat,
        const float* __restrict__ cnorm, float* __restrict__ counts,
        int* __restrict__ idxw, float* __restrict__ idxf,
        int* __restrict__ hardCnt, int* __restrict__ hardList) {
    __shared__ _Float16 As[8192];        // 128 x 64 halves, XOR-swizzled
    __shared__ _Float16 Bs[8192];
    __shared__ float wbuf[2][128][3];
    __shared__ float run[128][3];
    const int t = threadIdx.x;
    const int lane = t & 63, w = t >> 6;
    const int wm0 = (w & 1) * 64, wn0 = (w >> 1) * 64;
    const int row0 = blockIdx.x * 128;
    if (t < 128) { run[t][0] = 3.4e38f; run[t][1] = 0.f; run[t][2] = 3.4e38f; }

    int sA[4], mA[4], kgA[4];
    #pragma unroll
    for (int c = 0; c < 4; ++c) {
        int s = (w * 4 + c) * 64 + lane;
        sA[c] = s; mA[c] = s >> 3;
        kgA[c] = (((s & 7) ^ ((s >> 3) & 7)) << 3);
    }

    for (int ct = 0; ct < 8; ++ct) {
        const int cb0 = ct * 128;
        f32x4 acc[4][4];
        #pragma unroll
        for (int i = 0; i < 4; ++i)
            #pragma unroll
            for (int j = 0; j < 4; ++j) acc[i][j] = {0.f, 0.f, 0.f, 0.f};

        for (int ch = 0; ch < 12; ++ch) {
            const int seg = ch >> 2, dk = ch & 3;
            const int kA = (seg == 2 ? 256 : 0) + dk * 64;
            const int kB = (seg == 1 ? 256 : 0) + dk * 64;
            __syncthreads();
            #pragma unroll
            for (int c = 0; c < 4; ++c) {
                gl_lds16(Xcat + (size_t)(row0 + mA[c]) * 512 + kA + kgA[c], As + sA[c] * 8);
                gl_lds16(Ccat + (size_t)(cb0  + mA[c]) * 512 + kB + kgA[c], Bs + sA[c] * 8);
            }
            __syncthreads();
            #pragma unroll
            for (int ks = 0; ks < 2; ++ks) {
                h8 av[4], bv[4];
                const int kg = ks * 4 + (lane >> 4);
                #pragma unroll
                for (int f = 0; f < 4; ++f) {
                    int ma = wm0 + f * 16 + (lane & 15);
                    av[f] = *(const h8*)(As + ma * 64 + ((kg ^ (ma & 7)) << 3));
                    int nb = wn0 + f * 16 + (lane & 15);
                    bv[f] = *(const h8*)(Bs + nb * 64 + ((kg ^ (nb & 7)) << 3));
                }
                #pragma unroll
                for (int i = 0; i < 4; ++i)
                    #pragma unroll
                    for (int j = 0; j < 4; ++j)
                        acc[i][j] = __builtin_amdgcn_mfma_f32_16x16x32_f16(
                            av[i], bv[j], acc[i][j], 0, 0, 0);
            }
        }
        float cnv[4]; float gnf[4];
        #pragma unroll
        for (int fj = 0; fj < 4; ++fj) {
            int gn = cb0 + wn0 + fj * 16 + (lane & 15);
            gnf[fj] = (float)gn; cnv[fj] = cnorm[gn];
        }
        #pragma unroll
        for (int fi = 0; fi < 4; ++fi) {
            #pragma unroll
            for (int r = 0; r < 4; ++r) {
                float v1 = 3.4e38f, i1 = 0.f, v2 = 3.4e38f;
                #pragma unroll
                for (int fj = 0; fj < 4; ++fj) {
                    float q = fmaf(acc[fi][fj][r], -1.220703125e-4f, cnv[fj]);
                    merge2(v1, i1, v2, q, gnf[fj], 3.4e38f);
                }
                #pragma unroll
                for (int msk = 1; msk <= 8; msk <<= 1) {
                    float b1 = __shfl_xor(v1, msk, 64);
                    float bi = __shfl_xor(i1, msk, 64);
                    float b2 = __shfl_xor(v2, msk, 64);
                    merge2(v1, i1, v2, b1, bi, b2);
                }
                if ((lane & 15) == 0) {
                    int row = wm0 + fi * 16 + (lane >> 4) * 4 + r;
                    wbuf[w >> 1][row][0] = v1;
                    wbuf[w >> 1][row][1] = i1;
                    wbuf[w >> 1][row][2] = v2;
                }
            }
        }
        __syncthreads();
        if (t < 128) {
            float v1 = run[t][0], i1 = run[t][1], v2 = run[t][2];
            merge2(v1, i1, v2, wbuf[0][t][0], wbuf[0][t][1], wbuf[0][t][2]);
            merge2(v1, i1, v2, wbuf[1][t][0], wbuf[1][t][1], wbuf[1][t][2]);
            run[t][0] = v1; run[t][1] = i1; run[t][2] = v2;
        }
    }
    if (t < 128) {
        float v1 = run[t][0], fi1 = run[t][1], v2 = run[t][2];
        int i1 = (int)fi1;
        int n = row0 + t;
        idxf[n] = fi1; idxw[n] = i1;
        if (v2 - v1 > MARGIN) {
            unsafeAtomicAdd(&counts[i1], 1.0f);
        } else {
            int p = atomicAdd(hardCnt, 1);
            if (p < HCAP) hardList[p] = n;
            else unsafeAtomicAdd(&counts[i1], 1.0f);
        }
    }
}

// ---------------------------------------------------------------- exact ----
// Conflict-free d-major LDS layout; fmaf chain identical to proven chain.
__global__ __launch_bounds__(256) void vq_exact(
        const float* __restrict__ X, const float* __restrict__ cbT,
        const float* __restrict__ cnorm, const int* __restrict__ hardCnt,
        const int* __restrict__ hardList, float* __restrict__ counts,
        int* __restrict__ idxw, float* __restrict__ idxf) {
    __shared__ float xs[8][256];
    __shared__ float xnv[8];
    __shared__ float cbs[64 * 256];
    __shared__ int   toks[8];
    __shared__ float red[8][32][2];
    const int cnt = min(*hardCnt, HCAP);
    const int g0 = blockIdx.x * 8;
    if (g0 >= cnt) return;
    const int t = threadIdx.x;
    const int ntk = min(8, cnt - g0);
    if (t < 8) toks[t] = hardList[g0 + (t < ntk ? t : 0)];
    __syncthreads();
    {
        int tk = t >> 5, sl = t & 31;
        const float4* src = (const float4*)(X + (size_t)toks[tk] * 256);
        *(float4*)&xs[tk][sl * 8]     = src[sl * 2];
        *(float4*)&xs[tk][sl * 8 + 4] = src[sl * 2 + 1];
    }
    __syncthreads();
    if (t < 8) {
        #pragma clang fp contract(off)
        float tot = 0.f;
        #pragma unroll
        for (int h = 0; h < 2; ++h) {
            float r[8];
            #pragma unroll
            for (int j = 0; j < 8; ++j) { float a = xs[t][h * 128 + j]; float p = a * a; r[j] = p; }
            for (int i = 1; i < 16; ++i) {
                #pragma unroll
                for (int j = 0; j < 8; ++j) { float a = xs[t][h * 128 + i * 8 + j]; float p = a * a; r[j] = r[j] + p; }
            }
            float s = ((r[0] + r[1]) + (r[2] + r[3])) + ((r[4] + r[5]) + (r[6] + r[7]));
            tot = tot + s;
        }
        xnv[t] = tot;
    }
    float bS = 3.4e38f; float bI = 0.f;
    const int tk = t >> 5, tc = t & 31;
    const float4* cbT4 = (const float4*)cbT;
    for (int ch = 0; ch < 16; ++ch) {
        __syncthreads();
        {
            #pragma unroll
            for (int u = 0; u < 16; ++u) {
                int fid = u * 256 + t;
                int d = fid >> 4, c4 = fid & 15;
                ((float4*)cbs)[d * 16 + c4] = cbT4[(size_t)d * 256 + ch * 16 + c4];
            }
        }
        __syncthreads();
        {
            #pragma clang fp contract(off)
            float a0 = 0.f, a1 = 0.f;
            const float* xr = xs[tk];
            #pragma unroll 8
            for (int d4 = 0; d4 < 64; ++d4) {
                float4 xv = *(const float4*)(xr + 4 * d4);
                const float* cd = cbs + (4 * d4) * 64 + tc;
                a0 = fmaf(xv.x, cd[0],   a0);
                a1 = fmaf(xv.x, cd[32],  a1);
                a0 = fmaf(xv.y, cd[64],  a0);
                a1 = fmaf(xv.y, cd[96],  a1);
                a0 = fmaf(xv.z, cd[128], a0);
                a1 = fmaf(xv.z, cd[160], a1);
                a0 = fmaf(xv.w, cd[192], a0);
                a1 = fmaf(xv.w, cd[224], a1);
            }
            int gc0 = ch * 64 + tc, gc1 = gc0 + 32;
            float t1a = xnv[tk] + cnorm[gc0];
            float t2a = 2.0f * a0;
            float s0 = t1a - t2a;
            float t1b = xnv[tk] + cnorm[gc1];
            float t2b = 2.0f * a1;
            float s1 = t1b - t2b;
            if (s0 < bS) { bS = s0; bI = (float)gc0; }
            if (s1 < bS) { bS = s1; bI = (float)gc1; }
        }
    }
    __syncthreads();
    red[tk][tc][0] = bS; red[tk][tc][1] = bI;
    __syncthreads();
    if (t < ntk) {
        float v = 3.4e38f, bi = 0.f;
        for (int c = 0; c < 32; ++c) {
            float s = red[t][c][0], ii = red[t][c][1];
            if (s < v || (s == v && ii < bi)) { v = s; bi = ii; }
        }
        int n = toks[t];
        idxf[n] = bi; idxw[n] = (int)bi;
        unsafeAtomicAdd(&counts[(int)bi], 1.0f);
    }
}

// ---------------------------------------------------------------- scan ----
// offs/cursor = exclusive prefix sum of (int)counts. One block, 1024 thr.
__global__ __launch_bounds__(1024) void vq_scan(const float* __restrict__ counts,
                                                int* __restrict__ offs,
                                                int* __restrict__ cursor) {
    __shared__ int sc[1024];
    const int t = threadIdx.x;
    int c = (int)counts[t];
    sc[t] = c;
    __syncthreads();
    #pragma unroll
    for (int off = 1; off < 1024; off <<= 1) {
        int v = (t >= off) ? sc[t - off] : 0;
        __syncthreads();
        sc[t] += v;
        __syncthreads();
    }
    int excl = sc[t] - c;
    offs[t] = excl;
    cursor[t] = excl;
}

// ------------------------------------------------------------- scatter ----
__global__ __launch_bounds__(256) void vq_scatter(const int* __restrict__ idxw,
                                                  int* __restrict__ cursor,
                                                  int* __restrict__ sorted) {
    int n = blockIdx.x * 256 + threadIdx.x;
    int idx = idxw[n];
    int pos = atomicAdd(&cursor[idx], 1);
    sorted[pos] = n;
}

// ---------------------------------------------------------------- dw ------
// One block per code: segment-sum of X rows, zero atomics, coalesced.
__global__ __launch_bounds__(256) void vq_dw(const float* __restrict__ X,
                                             const int* __restrict__ offs,
                                             const float* __restrict__ counts,
                                             const int* __restrict__ sorted,
                                             float* __restrict__ dw) {
    const int k = blockIdx.x;
    const int t = threadIdx.x;
    const int begin = offs[k];
    const int cnt = (int)counts[k];
    const int* seg = sorted + begin;
    float acc = 0.f;
    int i = 0;
    for (; i + 4 <= cnt; i += 4) {
        int t0 = seg[i], t1 = seg[i + 1], t2 = seg[i + 2], t3 = seg[i + 3];
        float a = X[(size_t)t0 * 256 + t];
        float b = X[(size_t)t1 * 256 + t];
        float c = X[(size_t)t2 * 256 + t];
        float d = X[(size_t)t3 * 256 + t];
        acc += a; acc += b; acc += c; acc += d;
    }
    for (; i < cnt; ++i) acc += X[(size_t)seg[i] * 256 + t];
    dw[k * 256 + t] = acc;
}

// ---------------------------------------------------------------- out0 ----
// quantized_st + commitment loss (no dw atomics).
__global__ __launch_bounds__(256) void vq_out0(const float* __restrict__ X,
                                               const float* __restrict__ CB,
                                               const int* __restrict__ idxw,
                                               float* __restrict__ out0,
                                               float* __restrict__ loss) {
    const int t    = threadIdx.x;
    const int wave = (blockIdx.x * 256 + t) >> 6;
    const int lane = t & 63;
    const float4* X4 = reinterpret_cast<const float4*>(X);
    const float4* C4 = reinterpret_cast<const float4*>(CB);
    float4* O4 = reinterpret_cast<float4*>(out0);
    float lsum = 0.f;
    for (int r = 0; r < 64; ++r) {
        const int n = wave * 64 + r;
        const int idx = idxw[n];
        float4 x = X4[n * 64 + lane];
        float4 c = C4[idx * 64 + lane];
        float d0 = c.x - x.x, d1 = c.y - x.y, d2 = c.z - x.z, d3 = c.w - x.w;
        float4 q;
        q.x = x.x + d0; q.y = x.y + d1; q.z = x.z + d2; q.w = x.w + d3;
        O4[n * 64 + lane] = q;
        lsum += d0 * d0 + d1 * d1 + d2 * d2 + d3 * d3;
    }
    #pragma unroll
    for (int off = 32; off; off >>= 1) lsum += __shfl_down(lsum, off, 64);
    if (lane == 0) unsafeAtomicAdd(loss, lsum);
}

// ---------------------------------------------------------- finalize 1 ----
__global__ void vq_fin1(const float* __restrict__ counts,
                        const float* __restrict__ ecs,
                        const float* __restrict__ loss,
                        float* __restrict__ out1, float* __restrict__ out3,
                        float* __restrict__ out4) {
    __shared__ float sd[1024];
    const int t = threadIdx.x;
    float c   = counts[t];
    float pre = 0.99f * ecs[t] + 0.01f * c;
    sd[t] = pre; __syncthreads();
    for (int off = 512; off; off >>= 1) { if (t < off) sd[t] += sd[t + off]; __syncthreads(); }
    float n_total = sd[0];
    __syncthreads();
    float avg = c * (1.0f / 65536.0f);
    float ent = avg * logf(avg + 1e-10f);
    sd[t] = ent; __syncthreads();
    for (int off = 512; off; off >>= 1) { if (t < off) sd[t] += sd[t + off]; __syncthreads(); }
    float entsum = sd[0];
    float ncs = (pre + 1e-5f) / (n_total + 1024.0f * 1e-5f) * n_total;
    out4[t] = ncs;
    if (t == 0) {
        out1[0] = 0.25f * (loss[0] / 16777216.0f);
        out3[0] = expf(-entsum);
    }
}

// ---------------------------------------------------------- finalize 2 ----
__global__ __launch_bounds__(256) void vq_fin2(const float* __restrict__ emw,
                                               const float* __restrict__ dwv,
                                               const float* __restrict__ ncs,
                                               float* __restrict__ out5,
                                               float* __restrict__ out6) {
    int i = blockIdx.x * 256 + threadIdx.x;
    float e = 0.99f * emw[i] + 0.01f * dwv[i];
    out5[i] = e;
    out6[i] = e / ncs[i >> 8];
}

// ---------------------------------------------------------------- launch --
extern "C" void kernel_launch(void* const* d_in, const int* in_sizes, int n_in,
                              void* d_out, int out_size, void* d_ws, size_t ws_size,
                              hipStream_t stream) {
    const float* X   = (const float*)d_in[0];
    const float* CB  = (const float*)d_in[1];
    const float* ECS = (const float*)d_in[2];
    const float* EMW = (const float*)d_in[3];

    float* out0 = (float*)d_out;
    float* out1 = out0 + (size_t)NT * DD;
    float* out2 = out1 + 1;
    float* out3 = out2 + NT;
    float* out4 = out3 + 1;
    float* out5 = out4 + KC;
    float* out6 = out5 + (size_t)KC * DD;

    float* ws       = (float*)d_ws;
    float* counts   = ws + W_COUNTS;
    float* loss     = ws + W_LOSS;
    int*   hardCnt  = (int*)(ws + W_HCNT);
    float* cnorm    = ws + W_CNORM;
    int*   offs     = (int*)(ws + W_OFFS);
    int*   cursor   = (int*)(ws + W_CUR);
    int*   hardList = (int*)(ws + W_HLIST);
    int*   sorted   = (int*)(ws + W_SORT);
    int*   idxw     = (int*)(ws + W_IDX);
    float* dw       = ws + W_DWB;
    _Float16* Ccat  = (_Float16*)(ws + W_CCAT);
    float* cbT      = ws + W_CBT;

    // Xcat (67 MB halves) aliases out0: read in screen, out0 written later.
    _Float16* Xcat = (_Float16*)d_out;

    // zero counts + loss + hardCnt only (dw now fully written by vq_dw)
    (void)hipMemsetAsync(ws, 0, 1026 * sizeof(float), stream);

    vq_prepx<<<NT * DD / 4 / 256, 256, 0, stream>>>(X, Xcat);
    vq_prep<<<KC, 64, 0, stream>>>(CB, Ccat, cnorm, cbT);
    vq_screen<<<NT / 128, 256, 0, stream>>>(Xcat, Ccat, cnorm, counts, idxw, out2,
                                            hardCnt, hardList);
    vq_exact<<<HCAP / 8, 256, 0, stream>>>(X, cbT, cnorm, hardCnt, hardList,
                                           counts, idxw, out2);
    vq_scan<<<1, 1024, 0, stream>>>(counts, offs, cursor);
    vq_scatter<<<NT / 256, 256, 0, stream>>>(idxw, cursor, sorted);
    vq_dw<<<KC, 256, 0, stream>>>(X, offs, counts, sorted, dw);
    vq_out0<<<256, 256, 0, stream>>>(X, CB, idxw, out0, loss);
    vq_fin1<<<1, 1024, 0, stream>>>(counts, ECS, loss, out1, out3, out4);
    vq_fin2<<<KC * DD / 256, 256, 0, stream>>>(EMW, dw, out4, out5, out6);
}

// Round 6
// 398.299 us; speedup vs baseline: 2.6167x; 1.2774x over previous
//
#include <hip/hip_runtime.h>
#include <math.h>

// Problem constants
#define KC 1024
#define DD 256
#define NT 65536
#define MARGIN 2.5e-4f
#define HCAP 4096

// ws layout (in floats)
#define W_COUNTS 0            // float[1024]
#define W_LOSS   1024         // float[1]
#define W_HCNT   1025         // int[1]
#define W_CNORM  1028         // float[1024]
#define W_OFFS   2052         // int[1024]
#define W_CUR    3076         // int[1024]
#define W_HLIST  4100         // int[HCAP]
#define W_SORT   8196         // int[NT]
#define W_IDX    73732        // int[NT]
#define W_DWB    139268       // float[KC*DD]
#define W_AMIN   401412       // u64[HCAP] (8B aligned)
#define W_CCAT   409604       // fp16[KC*DD] hi-only (16B aligned)
#define W_CBT    540676       // float[DD*KC] d-major (16B aligned)
#define W_XH     802820       // float[HCAP*DD] (16B aligned)
// total: 1851396 floats (~7.4 MB)

typedef _Float16 h8 __attribute__((ext_vector_type(8)));
typedef _Float16 h4 __attribute__((ext_vector_type(4)));
typedef float f32x4 __attribute__((ext_vector_type(4)));
typedef unsigned long long u64;

__device__ __forceinline__ void gl_lds16(const _Float16* g, _Float16* l) {
    __builtin_amdgcn_global_load_lds(
        (const __attribute__((address_space(1))) unsigned int*)g,
        (__attribute__((address_space(3))) unsigned int*)l, 16, 0, 0);
}

__device__ __forceinline__ void merge2(float& v1, float& i1, float& v2,
                                       float b1, float bi, float b2) {
    if (b1 < v1) { v2 = fminf(v1, b2); v1 = b1; i1 = bi; }
    else         { v2 = fminf(v2, b1); }
}

__device__ __forceinline__ int physrow(int row, int d) {
    return ((((row >> 2) ^ ((d >> 2) & 7)) << 2) | (row & 3));
}

// ---------------------------------------------------------------- prepx ----
// Xcat[n][d] = fp16 hi of x (hi-only screen).
__global__ __launch_bounds__(256) void vq_prepx(const float* __restrict__ X,
                                                _Float16* __restrict__ Xcat) {
    int gid = blockIdx.x * 256 + threadIdx.x;        // 4,194,304 float4s
    float4 v = reinterpret_cast<const float4*>(X)[gid];
    int n = gid >> 6, d = (gid & 63) << 2;
    h4 hi;
    hi[0] = (_Float16)v.x; hi[1] = (_Float16)v.y;
    hi[2] = (_Float16)v.z; hi[3] = (_Float16)v.w;
    *(h4*)(Xcat + (size_t)n * 256 + d) = hi;
}

// ---------------------------------------------------------------- prep ----
// Ccat = fp16(codebook * 2^14) hi-only; cbT = d-major transpose (for exact);
// cnorm = EXACT round-1 computation.
__global__ __launch_bounds__(64) void vq_prep(const float* __restrict__ cb,
                                              _Float16* __restrict__ Ccat,
                                              float* __restrict__ cnorm,
                                              float* __restrict__ cbT) {
    const int k = blockIdx.x;
    const int l = threadIdx.x;
    float4 v = reinterpret_cast<const float4*>(cb)[k * 64 + l];
    cbT[(4 * l + 0) * KC + k] = v.x;
    cbT[(4 * l + 1) * KC + k] = v.y;
    cbT[(4 * l + 2) * KC + k] = v.z;
    cbT[(4 * l + 3) * KC + k] = v.w;
    h4 hi;
    hi[0] = (_Float16)(v.x * 16384.0f); hi[1] = (_Float16)(v.y * 16384.0f);
    hi[2] = (_Float16)(v.z * 16384.0f); hi[3] = (_Float16)(v.w * 16384.0f);
    *(h4*)(Ccat + (size_t)k * 256 + 4 * l) = hi;
    float s = v.x * v.x + v.y * v.y + v.z * v.z + v.w * v.w;
    #pragma unroll
    for (int off = 32; off; off >>= 1) s += __shfl_down(s, off, 64);
    if (l == 0) cnorm[k] = s;
}

// --------------------------------------------------------------- screen ----
// hi-only fp16 MFMA, K=256. Per-lane running top-2 in registers across all
// 8 col-tiles; single cross-lane reduction at the end.
__global__ __launch_bounds__(256) void vq_screen(
        const _Float16* __restrict__ Xcat, const _Float16* __restrict__ Ccat,
        const float* __restrict__ cnorm, float* __restrict__ counts,
        int* __restrict__ idxw, float* __restrict__ idxf,
        int* __restrict__ hardCnt, int* __restrict__ hardList) {
    __shared__ _Float16 As[8192];        // 128 rows x 64 halves, XOR-swizzled
    __shared__ _Float16 Bs[8192];
    __shared__ float wbuf[2][128][3];
    const int t = threadIdx.x;
    const int lane = t & 63, w = t >> 6;
    const int wm0 = (w & 1) * 64, wn0 = (w >> 1) * 64;
    const int row0 = blockIdx.x * 128;

    int sA[4], mA[4], kgA[4];
    #pragma unroll
    for (int c = 0; c < 4; ++c) {
        int s = (w * 4 + c) * 64 + lane;
        sA[c] = s; mA[c] = s >> 3;
        kgA[c] = (((s & 7) ^ ((s >> 3) & 7)) << 3);
    }

    float rv1[16], ri1[16], rv2[16];
    #pragma unroll
    for (int i = 0; i < 16; ++i) { rv1[i] = 3.4e38f; ri1[i] = 0.f; rv2[i] = 3.4e38f; }

    for (int ct = 0; ct < 8; ++ct) {
        const int cb0 = ct * 128;
        f32x4 acc[4][4];
        #pragma unroll
        for (int i = 0; i < 4; ++i)
            #pragma unroll
            for (int j = 0; j < 4; ++j) acc[i][j] = {0.f, 0.f, 0.f, 0.f};

        for (int dk = 0; dk < 4; ++dk) {
            const int kk = dk * 64;
            __syncthreads();
            #pragma unroll
            for (int c = 0; c < 4; ++c) {
                gl_lds16(Xcat + (size_t)(row0 + mA[c]) * 256 + kk + kgA[c], As + sA[c] * 8);
                gl_lds16(Ccat + (size_t)(cb0  + mA[c]) * 256 + kk + kgA[c], Bs + sA[c] * 8);
            }
            __syncthreads();
            #pragma unroll
            for (int ks = 0; ks < 2; ++ks) {
                h8 av[4], bv[4];
                const int kg = ks * 4 + (lane >> 4);
                #pragma unroll
                for (int f = 0; f < 4; ++f) {
                    int ma = wm0 + f * 16 + (lane & 15);
                    av[f] = *(const h8*)(As + ma * 64 + ((kg ^ (ma & 7)) << 3));
                    int nb = wn0 + f * 16 + (lane & 15);
                    bv[f] = *(const h8*)(Bs + nb * 64 + ((kg ^ (nb & 7)) << 3));
                }
                #pragma unroll
                for (int i = 0; i < 4; ++i)
                    #pragma unroll
                    for (int j = 0; j < 4; ++j)
                        acc[i][j] = __builtin_amdgcn_mfma_f32_16x16x32_f16(
                            av[i], bv[j], acc[i][j], 0, 0, 0);
            }
        }
        // epilogue into registers: q = cn - acc*2^-13
        float cnv[4]; float gnf[4];
        #pragma unroll
        for (int fj = 0; fj < 4; ++fj) {
            int gn = cb0 + wn0 + fj * 16 + (lane & 15);
            gnf[fj] = (float)gn; cnv[fj] = cnorm[gn];
        }
        #pragma unroll
        for (int fi = 0; fi < 4; ++fi) {
            #pragma unroll
            for (int r = 0; r < 4; ++r) {
                const int ix = fi * 4 + r;
                #pragma unroll
                for (int fj = 0; fj < 4; ++fj) {
                    float q = fmaf(acc[fi][fj][r], -1.220703125e-4f, cnv[fj]);
                    merge2(rv1[ix], ri1[ix], rv2[ix], q, gnf[fj], 3.4e38f);
                }
            }
        }
    }
    // single cross-lane reduction
    #pragma unroll
    for (int fi = 0; fi < 4; ++fi) {
        #pragma unroll
        for (int r = 0; r < 4; ++r) {
            const int ix = fi * 4 + r;
            float v1 = rv1[ix], i1 = ri1[ix], v2 = rv2[ix];
            #pragma unroll
            for (int msk = 1; msk <= 8; msk <<= 1) {
                float b1 = __shfl_xor(v1, msk, 64);
                float bi = __shfl_xor(i1, msk, 64);
                float b2 = __shfl_xor(v2, msk, 64);
                merge2(v1, i1, v2, b1, bi, b2);
            }
            if ((lane & 15) == 0) {
                int row = wm0 + fi * 16 + (lane >> 4) * 4 + r;
                wbuf[w >> 1][row][0] = v1;
                wbuf[w >> 1][row][1] = i1;
                wbuf[w >> 1][row][2] = v2;
            }
        }
    }
    __syncthreads();
    if (t < 128) {
        float v1 = wbuf[0][t][0], i1 = wbuf[0][t][1], v2 = wbuf[0][t][2];
        merge2(v1, i1, v2, wbuf[1][t][0], wbuf[1][t][1], wbuf[1][t][2]);
        int i1i = (int)i1;
        int n = row0 + t;
        idxf[n] = i1; idxw[n] = i1i;
        if (v2 - v1 > MARGIN) {
            unsafeAtomicAdd(&counts[i1i], 1.0f);
        } else {
            int p = atomicAdd(hardCnt, 1);
            if (p < HCAP) hardList[p] = n;
            else unsafeAtomicAdd(&counts[i1i], 1.0f);
        }
    }
}

// -------------------------------------------------------------- compact ----
// Gather hard-token rows into Xh (zero-pad unused slots).
__global__ __launch_bounds__(256) void vq_compact(const float* __restrict__ X,
                                                  const int* __restrict__ hardCnt,
                                                  const int* __restrict__ hardList,
                                                  float* __restrict__ Xh) {
    const int cnt = min(*hardCnt, HCAP);
    const int i = blockIdx.x * 4 + (threadIdx.x >> 6);
    const int lane = threadIdx.x & 63;
    float4 v = {0.f, 0.f, 0.f, 0.f};
    if (i < cnt) v = ((const float4*)(X + (size_t)hardList[i] * 256))[lane];
    ((float4*)(Xh + (size_t)i * 256))[lane] = v;
}

// ---------------------------------------------------------------- exact ----
// Round-1 proven fp32 GEMM structure on compacted hard tokens.
// Block = 128 token-slots (blockIdx.x) x 128 codes (blockIdx.y).
// Chain per (token,code) byte-identical to round-1: swizzled A, pairwise-tree
// xn, d-sequential fmaf, contract-off epilogue. Per-row argmin via u64
// atomicMin on (score_bits<<32 | code): scores >0 so bits are monotonic;
// lexicographic min == numpy first-occurrence argmin.
__global__ __launch_bounds__(256) void vq_exact(const float* __restrict__ Xh,
                                                const float* __restrict__ cbT,
                                                const float* __restrict__ cnorm,
                                                const int* __restrict__ hardCnt,
                                                u64* __restrict__ amin) {
    extern __shared__ float smem[];
    float* As = smem;              // 256*128 = 32768 floats
    float* Bs = smem + 32768;      // 32*128  = 4096  floats
    float* xn = smem + 36992 - 128;
    const int cnt = min(*hardCnt, HCAP);
    const int row0 = blockIdx.x * 128;
    if (row0 >= cnt) return;
    const int ct = blockIdx.y;     // code tile 0..7
    const int t  = threadIdx.x;
    const int tx = t & 15;
    const int ty = t >> 4;

    const float4* X4 = reinterpret_cast<const float4*>(Xh);
    #pragma unroll 4
    for (int p = 0; p < 32; ++p) {
        int fid = p * 256 + t;
        int row = fid >> 6;
        int d4  = fid & 63;
        float4 v = X4[(size_t)row0 * 64 + (size_t)row * 64 + d4];
        int d = d4 << 2;
        int ph = physrow(row, d);
        As[(d + 0) * 128 + ph] = v.x;
        As[(d + 1) * 128 + ph] = v.y;
        As[(d + 2) * 128 + ph] = v.z;
        As[(d + 3) * 128 + ph] = v.w;
    }
    __syncthreads();

    if (t < 128) {
        #pragma clang fp contract(off)
        float tot = 0.f;
        #pragma unroll
        for (int h = 0; h < 2; ++h) {
            float r[8];
            #pragma unroll
            for (int j = 0; j < 8; ++j) {
                int d = h * 128 + j;
                float a = As[d * 128 + physrow(t, d)];
                float p = a * a;
                r[j] = p;
            }
            for (int i = 1; i < 16; ++i) {
                #pragma unroll
                for (int j = 0; j < 8; ++j) {
                    int d = h * 128 + i * 8 + j;
                    float a = As[d * 128 + physrow(t, d)];
                    float p = a * a;
                    r[j] = r[j] + p;
                }
            }
            float s = ((r[0] + r[1]) + (r[2] + r[3])) + ((r[4] + r[5]) + (r[6] + r[7]));
            tot = tot + s;
        }
        xn[t] = tot;
    }

    float acc[8][8];
    #pragma unroll
    for (int i = 0; i < 8; ++i)
        #pragma unroll
        for (int j = 0; j < 8; ++j) acc[i][j] = 0.f;

    const float4* cbT4 = reinterpret_cast<const float4*>(cbT);

    #pragma unroll 1
    for (int dk = 0; dk < 8; ++dk) {
        __syncthreads();
        #pragma unroll
        for (int it = 0; it < 4; ++it) {
            int fid = it * 256 + t;
            int dd  = fid >> 5;
            int c4  = fid & 31;
            float4 v = cbT4[(size_t)(dk * 32 + dd) * 256 + ct * 32 + c4];
            reinterpret_cast<float4*>(Bs)[dd * 32 + c4] = v;
        }
        __syncthreads();

        #pragma unroll 8
        for (int dd = 0; dd < 32; ++dd) {
            const int d  = dk * 32 + dd;
            const int sw = (dd >> 2) & 7;
            const int ar = ((ty ^ sw) << 2);
            const float4 a0 = *reinterpret_cast<const float4*>(&As[d * 128 + ar]);
            const float4 a1 = *reinterpret_cast<const float4*>(&As[d * 128 + ar + 64]);
            const float4 b0 = *reinterpret_cast<const float4*>(&Bs[dd * 128 + (tx << 2)]);
            const float4 b1 = *reinterpret_cast<const float4*>(&Bs[dd * 128 + (tx << 2) + 64]);
            const float av[8] = {a0.x, a0.y, a0.z, a0.w, a1.x, a1.y, a1.z, a1.w};
            const float bv[8] = {b0.x, b0.y, b0.z, b0.w, b1.x, b1.y, b1.z, b1.w};
            #pragma unroll
            for (int i = 0; i < 8; ++i)
                #pragma unroll
                for (int j = 0; j < 8; ++j)
                    acc[i][j] = fmaf(av[i], bv[j], acc[i][j]);
        }
    }

    u64 emin[8];
    #pragma unroll
    for (int i = 0; i < 8; ++i) emin[i] = ~0ull;
    {
        #pragma clang fp contract(off)
        float cnv[8];
        int   gcl[8];
        #pragma unroll
        for (int j = 0; j < 8; ++j) {
            int cl = (j < 4) ? (tx * 4 + j) : (64 + tx * 4 + (j - 4));
            gcl[j] = ct * 128 + cl;
            cnv[j] = cnorm[gcl[j]];
        }
        #pragma unroll
        for (int i = 0; i < 8; ++i) {
            int rowl = (i < 4) ? (ty * 4 + i) : (64 + ty * 4 + (i - 4));
            float xr = xn[rowl];
            #pragma unroll
            for (int j = 0; j < 8; ++j) {
                float t1 = xr + cnv[j];
                float t2 = 2.0f * acc[i][j];
                float s  = t1 - t2;
                u64 enc = ((u64)__float_as_uint(s) << 32) | (unsigned int)gcl[j];
                if (enc < emin[i]) emin[i] = enc;
            }
        }
    }
    __syncthreads();
    u64* red = reinterpret_cast<u64*>(Bs);   // 128 x 16 u64 = 16 KB
    #pragma unroll
    for (int i = 0; i < 8; ++i) {
        int rowl = (i < 4) ? (ty * 4 + i) : (64 + ty * 4 + (i - 4));
        red[rowl * 16 + tx] = emin[i];
    }
    __syncthreads();
    if (t < 128) {
        u64 m = ~0ull;
        #pragma unroll
        for (int x = 0; x < 16; ++x) m = min(m, red[t * 16 + x]);
        atomicMin(&amin[row0 + t], m);
    }
}

// ---------------------------------------------------------------- fixup ----
__global__ __launch_bounds__(256) void vq_fixup(const int* __restrict__ hardCnt,
                                                const int* __restrict__ hardList,
                                                const u64* __restrict__ amin,
                                                float* __restrict__ counts,
                                                int* __restrict__ idxw,
                                                float* __restrict__ idxf) {
    const int cnt = min(*hardCnt, HCAP);
    int i = blockIdx.x * 256 + threadIdx.x;
    if (i >= cnt) return;
    int tok = hardList[i];
    int code = (int)(amin[i] & 0xFFFFFFFFull);
    idxf[tok] = (float)code;
    idxw[tok] = code;
    unsafeAtomicAdd(&counts[code], 1.0f);
}

// ---------------------------------------------------------------- scan ----
__global__ __launch_bounds__(1024) void vq_scan(const float* __restrict__ counts,
                                                int* __restrict__ offs,
                                                int* __restrict__ cursor) {
    __shared__ int sc[1024];
    const int t = threadIdx.x;
    int c = (int)counts[t];
    sc[t] = c;
    __syncthreads();
    #pragma unroll
    for (int off = 1; off < 1024; off <<= 1) {
        int v = (t >= off) ? sc[t - off] : 0;
        __syncthreads();
        sc[t] += v;
        __syncthreads();
    }
    int excl = sc[t] - c;
    offs[t] = excl;
    cursor[t] = excl;
}

// ------------------------------------------------------------- scatter ----
__global__ __launch_bounds__(256) void vq_scatter(const int* __restrict__ idxw,
                                                  int* __restrict__ cursor,
                                                  int* __restrict__ sorted) {
    int n = blockIdx.x * 256 + threadIdx.x;
    int idx = idxw[n];
    int pos = atomicAdd(&cursor[idx], 1);
    sorted[pos] = n;
}

// ---------------------------------------------------------------- dw ------
__global__ __launch_bounds__(256) void vq_dw(const float* __restrict__ X,
                                             const int* __restrict__ offs,
                                             const float* __restrict__ counts,
                                             const int* __restrict__ sorted,
                                             float* __restrict__ dw) {
    const int k = blockIdx.x;
    const int t = threadIdx.x;
    const int begin = offs[k];
    const int cnt = (int)counts[k];
    const int* seg = sorted + begin;
    float acc = 0.f;
    int i = 0;
    for (; i + 4 <= cnt; i += 4) {
        int t0 = seg[i], t1 = seg[i + 1], t2 = seg[i + 2], t3 = seg[i + 3];
        float a = X[(size_t)t0 * 256 + t];
        float b = X[(size_t)t1 * 256 + t];
        float c = X[(size_t)t2 * 256 + t];
        float d = X[(size_t)t3 * 256 + t];
        acc += a; acc += b; acc += c; acc += d;
    }
    for (; i < cnt; ++i) acc += X[(size_t)seg[i] * 256 + t];
    dw[k * 256 + t] = acc;
}

// ---------------------------------------------------------------- out0 ----
__global__ __launch_bounds__(256) void vq_out0(const float* __restrict__ X,
                                               const float* __restrict__ CB,
                                               const int* __restrict__ idxw,
                                               float* __restrict__ out0,
                                               float* __restrict__ loss) {
    const int t    = threadIdx.x;
    const int wave = (blockIdx.x * 256 + t) >> 6;
    const int lane = t & 63;
    const float4* X4 = reinterpret_cast<const float4*>(X);
    const float4* C4 = reinterpret_cast<const float4*>(CB);
    float4* O4 = reinterpret_cast<float4*>(out0);
    float lsum = 0.f;
    for (int r = 0; r < 64; ++r) {
        const int n = wave * 64 + r;
        const int idx = idxw[n];
        float4 x = X4[n * 64 + lane];
        float4 c = C4[idx * 64 + lane];
        float d0 = c.x - x.x, d1 = c.y - x.y, d2 = c.z - x.z, d3 = c.w - x.w;
        float4 q;
        q.x = x.x + d0; q.y = x.y + d1; q.z = x.z + d2; q.w = x.w + d3;
        O4[n * 64 + lane] = q;
        lsum += d0 * d0 + d1 * d1 + d2 * d2 + d3 * d3;
    }
    #pragma unroll
    for (int off = 32; off; off >>= 1) lsum += __shfl_down(lsum, off, 64);
    if (lane == 0) unsafeAtomicAdd(loss, lsum);
}

// ---------------------------------------------------------- finalize 1 ----
__global__ void vq_fin1(const float* __restrict__ counts,
                        const float* __restrict__ ecs,
                        const float* __restrict__ loss,
                        float* __restrict__ out1, float* __restrict__ out3,
                        float* __restrict__ out4) {
    __shared__ float sd[1024];
    const int t = threadIdx.x;
    float c   = counts[t];
    float pre = 0.99f * ecs[t] + 0.01f * c;
    sd[t] = pre; __syncthreads();
    for (int off = 512; off; off >>= 1) { if (t < off) sd[t] += sd[t + off]; __syncthreads(); }
    float n_total = sd[0];
    __syncthreads();
    float avg = c * (1.0f / 65536.0f);
    float ent = avg * logf(avg + 1e-10f);
    sd[t] = ent; __syncthreads();
    for (int off = 512; off; off >>= 1) { if (t < off) sd[t] += sd[t + off]; __syncthreads(); }
    float entsum = sd[0];
    float ncs = (pre + 1e-5f) / (n_total + 1024.0f * 1e-5f) * n_total;
    out4[t] = ncs;
    if (t == 0) {
        out1[0] = 0.25f * (loss[0] / 16777216.0f);
        out3[0] = expf(-entsum);
    }
}

// ---------------------------------------------------------- finalize 2 ----
__global__ __launch_bounds__(256) void vq_fin2(const float* __restrict__ emw,
                                               const float* __restrict__ dwv,
                                               const float* __restrict__ ncs,
                                               float* __restrict__ out5,
                                               float* __restrict__ out6) {
    int i = blockIdx.x * 256 + threadIdx.x;
    float e = 0.99f * emw[i] + 0.01f * dwv[i];
    out5[i] = e;
    out6[i] = e / ncs[i >> 8];
}

// ---------------------------------------------------------------- launch --
extern "C" void kernel_launch(void* const* d_in, const int* in_sizes, int n_in,
                              void* d_out, int out_size, void* d_ws, size_t ws_size,
                              hipStream_t stream) {
    const float* X   = (const float*)d_in[0];
    const float* CB  = (const float*)d_in[1];
    const float* ECS = (const float*)d_in[2];
    const float* EMW = (const float*)d_in[3];

    float* out0 = (float*)d_out;
    float* out1 = out0 + (size_t)NT * DD;
    float* out2 = out1 + 1;
    float* out3 = out2 + NT;
    float* out4 = out3 + 1;
    float* out5 = out4 + KC;
    float* out6 = out5 + (size_t)KC * DD;

    float* ws       = (float*)d_ws;
    float* counts   = ws + W_COUNTS;
    float* loss     = ws + W_LOSS;
    int*   hardCnt  = (int*)(ws + W_HCNT);
    float* cnorm    = ws + W_CNORM;
    int*   offs     = (int*)(ws + W_OFFS);
    int*   cursor   = (int*)(ws + W_CUR);
    int*   hardList = (int*)(ws + W_HLIST);
    int*   sorted   = (int*)(ws + W_SORT);
    int*   idxw     = (int*)(ws + W_IDX);
    float* dw       = ws + W_DWB;
    u64*   amin     = (u64*)(ws + W_AMIN);
    _Float16* Ccat  = (_Float16*)(ws + W_CCAT);
    float* cbT      = ws + W_CBT;
    float* Xh       = ws + W_XH;

    // Xcat (33.5 MB halves) aliases out0: read by screen, out0 written later.
    _Float16* Xcat = (_Float16*)d_out;

    (void)hipMemsetAsync(ws, 0, 1026 * sizeof(float), stream);
    (void)hipMemsetAsync(amin, 0xFF, (size_t)HCAP * 8, stream);

    vq_prepx<<<NT * DD / 4 / 256, 256, 0, stream>>>(X, Xcat);
    vq_prep<<<KC, 64, 0, stream>>>(CB, Ccat, cnorm, cbT);
    vq_screen<<<NT / 128, 256, 0, stream>>>(Xcat, Ccat, cnorm, counts, idxw, out2,
                                            hardCnt, hardList);
    vq_compact<<<HCAP / 4, 256, 0, stream>>>(X, hardCnt, hardList, Xh);
    vq_exact<<<dim3(HCAP / 128, 8), 256, 36992 * sizeof(float), stream>>>(
        Xh, cbT, cnorm, hardCnt, amin);
    vq_fixup<<<HCAP / 256, 256, 0, stream>>>(hardCnt, hardList, amin, counts,
                                             idxw, out2);
    vq_scan<<<1, 1024, 0, stream>>>(counts, offs, cursor);
    vq_scatter<<<NT / 256, 256, 0, stream>>>(idxw, cursor, sorted);
    vq_dw<<<KC, 256, 0, stream>>>(X, offs, counts, sorted, dw);
    vq_out0<<<256, 256, 0, stream>>>(X, CB, idxw, out0, loss);
    vq_fin1<<<1, 1024, 0, stream>>>(counts, ECS, loss, out1, out3, out4);
    vq_fin2<<<KC * DD / 256, 256, 0, stream>>>(EMW, dw, out4, out5, out6);
}

// Round 7
// 395.719 us; speedup vs baseline: 2.6337x; 1.0065x over previous
//
#include <hip/hip_runtime.h>
#include <math.h>

// Problem constants
#define KC 1024
#define DD 256
#define NT 65536
#define MARGIN 2.5e-4f
#define HCAP 4096

// ws layout (in floats)
#define W_COUNTS 0            // float[1024]
#define W_LOSS   1024         // float[1]
#define W_HCNT   1025         // int[1]
#define W_CNORM  1028         // float[1024]
#define W_OFFS   2052         // int[1024]
#define W_CUR    3076         // int[1024]
#define W_HLIST  4100         // int[HCAP]
#define W_SORT   8196         // int[NT]
#define W_IDX    73732        // int[NT]
#define W_DWB    139268       // float[KC*DD]
#define W_AMIN   401412       // u64[HCAP] (8B aligned)
#define W_CCAT   409604       // fp16[KC*DD] hi-only (16B aligned)
#define W_CBT    540676       // float[DD*KC] d-major (16B aligned)
#define W_XH     802820       // float[HCAP*DD] (16B aligned)
// total: 1851396 floats (~7.4 MB)

typedef _Float16 h8 __attribute__((ext_vector_type(8)));
typedef _Float16 h4 __attribute__((ext_vector_type(4)));
typedef float f32x4 __attribute__((ext_vector_type(4)));
typedef unsigned long long u64;

__device__ __forceinline__ void gl_lds16(const _Float16* g, _Float16* l) {
    __builtin_amdgcn_global_load_lds(
        (const __attribute__((address_space(1))) unsigned int*)g,
        (__attribute__((address_space(3))) unsigned int*)l, 16, 0, 0);
}

__device__ __forceinline__ void merge2(float& v1, float& i1, float& v2,
                                       float b1, float bi, float b2) {
    if (b1 < v1) { v2 = fminf(v1, b2); v1 = b1; i1 = bi; }
    else         { v2 = fminf(v2, b1); }
}

__device__ __forceinline__ int physrow(int row, int d) {
    return ((((row >> 2) ^ ((d >> 2) & 7)) << 2) | (row & 3));
}

// ---------------------------------------------------------------- prepx ----
// Xcat[n][d] = fp16 hi of x (hi-only screen).
__global__ __launch_bounds__(256) void vq_prepx(const float* __restrict__ X,
                                                _Float16* __restrict__ Xcat) {
    int gid = blockIdx.x * 256 + threadIdx.x;        // 4,194,304 float4s
    float4 v = reinterpret_cast<const float4*>(X)[gid];
    int n = gid >> 6, d = (gid & 63) << 2;
    h4 hi;
    hi[0] = (_Float16)v.x; hi[1] = (_Float16)v.y;
    hi[2] = (_Float16)v.z; hi[3] = (_Float16)v.w;
    *(h4*)(Xcat + (size_t)n * 256 + d) = hi;
}

// ---------------------------------------------------------------- prep ----
// Ccat = fp16(codebook * 2^14) hi-only; cbT = d-major transpose (for exact);
// cnorm = EXACT round-1 computation.
__global__ __launch_bounds__(64) void vq_prep(const float* __restrict__ cb,
                                              _Float16* __restrict__ Ccat,
                                              float* __restrict__ cnorm,
                                              float* __restrict__ cbT) {
    const int k = blockIdx.x;
    const int l = threadIdx.x;
    float4 v = reinterpret_cast<const float4*>(cb)[k * 64 + l];
    cbT[(4 * l + 0) * KC + k] = v.x;
    cbT[(4 * l + 1) * KC + k] = v.y;
    cbT[(4 * l + 2) * KC + k] = v.z;
    cbT[(4 * l + 3) * KC + k] = v.w;
    h4 hi;
    hi[0] = (_Float16)(v.x * 16384.0f); hi[1] = (_Float16)(v.y * 16384.0f);
    hi[2] = (_Float16)(v.z * 16384.0f); hi[3] = (_Float16)(v.w * 16384.0f);
    *(h4*)(Ccat + (size_t)k * 256 + 4 * l) = hi;
    float s = v.x * v.x + v.y * v.y + v.z * v.z + v.w * v.w;
    #pragma unroll
    for (int off = 32; off; off >>= 1) s += __shfl_down(s, off, 64);
    if (l == 0) cnorm[k] = s;
}

// --------------------------------------------------------------- screen ----
// hi-only fp16 MFMA, K=256. A staged ONCE full-K (64 KB); B double-buffered
// 128-code x 128-half chunks (2x32 KB); 1 barrier / iteration (16 total),
// prefetch hides L2 latency. Per-lane register top-2, single reduction.
__global__ __launch_bounds__(256, 1) void vq_screen(
        const _Float16* __restrict__ Xcat, const _Float16* __restrict__ Ccat,
        const float* __restrict__ cnorm, float* __restrict__ counts,
        int* __restrict__ idxw, float* __restrict__ idxf,
        int* __restrict__ hardCnt, int* __restrict__ hardList) {
    __shared__ _Float16 As[32768];       // 128 rows x 256 halves, swizzled
    __shared__ _Float16 Bs[2][16384];    // 2 x (128 codes x 128 halves)
    __shared__ float wbuf[2][128][3];
    const int t = threadIdx.x;
    const int lane = t & 63, w = t >> 6;
    const int wm0 = (w & 1) * 64, wn0 = (w >> 1) * 64;
    const int row0 = blockIdx.x * 128;

    // ---- stage A (once): slot s -> row=s>>5, phys granule=s&31,
    // logical granule = phys ^ (row&7). 16 B per slot.
    #pragma unroll
    for (int r = 0; r < 16; ++r) {
        int s = r * 256 + t;
        int row = s >> 5, gp = s & 31;
        int gl = gp ^ (row & 7);
        gl_lds16(Xcat + (size_t)(row0 + row) * 256 + gl * 8, As + s * 8);
    }
    // ---- stage B chunk 0
    {
        #pragma unroll
        for (int r = 0; r < 8; ++r) {
            int s = r * 256 + t;
            int code = s >> 4, gp = s & 15;
            int gl = gp ^ (code & 7);
            gl_lds16(Ccat + (size_t)code * 256 + gl * 8, Bs[0] + s * 8);
        }
    }
    __syncthreads();

    float rv1[16], ri1[16], rv2[16];
    #pragma unroll
    for (int i = 0; i < 16; ++i) { rv1[i] = 3.4e38f; ri1[i] = 0.f; rv2[i] = 3.4e38f; }

    f32x4 acc[4][4];

    #pragma unroll 1
    for (int it = 0; it < 16; ++it) {
        const int ct = it >> 1, c = it & 1;
        // prefetch next B chunk into the other buffer
        if (it + 1 < 16) {
            const int jn = it + 1;
            const int cb0n = (jn >> 1) * 128;
            const int khn  = (jn & 1) * 128;
            _Float16* Bn = Bs[jn & 1];
            #pragma unroll
            for (int r = 0; r < 8; ++r) {
                int s = r * 256 + t;
                int code = s >> 4, gp = s & 15;
                int gl = gp ^ (code & 7);
                gl_lds16(Ccat + (size_t)(cb0n + code) * 256 + khn + gl * 8,
                         Bn + s * 8);
            }
        }
        if (c == 0) {
            #pragma unroll
            for (int i = 0; i < 4; ++i)
                #pragma unroll
                for (int j = 0; j < 4; ++j) acc[i][j] = {0.f, 0.f, 0.f, 0.f};
        }
        const _Float16* Bc = Bs[it & 1];
        #pragma unroll
        for (int ks = 0; ks < 4; ++ks) {
            h8 av[4], bv[4];
            const int kq = ks * 4 + (lane >> 4);   // 0..15 within chunk
            const int kg = c * 16 + kq;            // 0..31 global (A)
            #pragma unroll
            for (int f = 0; f < 4; ++f) {
                int ma = wm0 + f * 16 + (lane & 15);
                av[f] = *(const h8*)(As + ma * 256 + ((kg ^ (ma & 7)) << 3));
                int nb = wn0 + f * 16 + (lane & 15);
                bv[f] = *(const h8*)(Bc + nb * 128 + ((kq ^ (nb & 7)) << 3));
            }
            #pragma unroll
            for (int i = 0; i < 4; ++i)
                #pragma unroll
                for (int j = 0; j < 4; ++j)
                    acc[i][j] = __builtin_amdgcn_mfma_f32_16x16x32_f16(
                        av[i], bv[j], acc[i][j], 0, 0, 0);
        }
        if (c == 1) {
            // epilogue into registers: q = cn - acc*2^-13
            const int cb0 = ct * 128;
            float cnv[4]; float gnf[4];
            #pragma unroll
            for (int fj = 0; fj < 4; ++fj) {
                int gn = cb0 + wn0 + fj * 16 + (lane & 15);
                gnf[fj] = (float)gn; cnv[fj] = cnorm[gn];
            }
            #pragma unroll
            for (int fi = 0; fi < 4; ++fi) {
                #pragma unroll
                for (int r = 0; r < 4; ++r) {
                    const int ix = fi * 4 + r;
                    #pragma unroll
                    for (int fj = 0; fj < 4; ++fj) {
                        float q = fmaf(acc[fi][fj][r], -1.220703125e-4f, cnv[fj]);
                        merge2(rv1[ix], ri1[ix], rv2[ix], q, gnf[fj], 3.4e38f);
                    }
                }
            }
        }
        __syncthreads();
    }

    // single cross-lane reduction
    #pragma unroll
    for (int fi = 0; fi < 4; ++fi) {
        #pragma unroll
        for (int r = 0; r < 4; ++r) {
            const int ix = fi * 4 + r;
            float v1 = rv1[ix], i1 = ri1[ix], v2 = rv2[ix];
            #pragma unroll
            for (int msk = 1; msk <= 8; msk <<= 1) {
                float b1 = __shfl_xor(v1, msk, 64);
                float bi = __shfl_xor(i1, msk, 64);
                float b2 = __shfl_xor(v2, msk, 64);
                merge2(v1, i1, v2, b1, bi, b2);
            }
            if ((lane & 15) == 0) {
                int row = wm0 + fi * 16 + (lane >> 4) * 4 + r;
                wbuf[w >> 1][row][0] = v1;
                wbuf[w >> 1][row][1] = i1;
                wbuf[w >> 1][row][2] = v2;
            }
        }
    }
    __syncthreads();
    if (t < 128) {
        float v1 = wbuf[0][t][0], i1 = wbuf[0][t][1], v2 = wbuf[0][t][2];
        merge2(v1, i1, v2, wbuf[1][t][0], wbuf[1][t][1], wbuf[1][t][2]);
        int i1i = (int)i1;
        int n = row0 + t;
        idxf[n] = i1; idxw[n] = i1i;
        if (v2 - v1 > MARGIN) {
            unsafeAtomicAdd(&counts[i1i], 1.0f);
        } else {
            int p = atomicAdd(hardCnt, 1);
            if (p < HCAP) hardList[p] = n;
            else unsafeAtomicAdd(&counts[i1i], 1.0f);
        }
    }
}

// -------------------------------------------------------------- compact ----
__global__ __launch_bounds__(256) void vq_compact(const float* __restrict__ X,
                                                  const int* __restrict__ hardCnt,
                                                  const int* __restrict__ hardList,
                                                  float* __restrict__ Xh) {
    const int cnt = min(*hardCnt, HCAP);
    const int i = blockIdx.x * 4 + (threadIdx.x >> 6);
    const int lane = threadIdx.x & 63;
    float4 v = {0.f, 0.f, 0.f, 0.f};
    if (i < cnt) v = ((const float4*)(X + (size_t)hardList[i] * 256))[lane];
    ((float4*)(Xh + (size_t)i * 256))[lane] = v;
}

// ---------------------------------------------------------------- exact ----
// Round-1 proven fp32 GEMM structure on compacted hard tokens.
__global__ __launch_bounds__(256) void vq_exact(const float* __restrict__ Xh,
                                                const float* __restrict__ cbT,
                                                const float* __restrict__ cnorm,
                                                const int* __restrict__ hardCnt,
                                                u64* __restrict__ amin) {
    extern __shared__ float smem[];
    float* As = smem;              // 256*128 = 32768 floats
    float* Bs = smem + 32768;      // 32*128  = 4096  floats
    float* xn = smem + 36992 - 128;
    const int cnt = min(*hardCnt, HCAP);
    const int row0 = blockIdx.x * 128;
    if (row0 >= cnt) return;
    const int ct = blockIdx.y;     // code tile 0..7
    const int t  = threadIdx.x;
    const int tx = t & 15;
    const int ty = t >> 4;

    const float4* X4 = reinterpret_cast<const float4*>(Xh);
    #pragma unroll 4
    for (int p = 0; p < 32; ++p) {
        int fid = p * 256 + t;
        int row = fid >> 6;
        int d4  = fid & 63;
        float4 v = X4[(size_t)row0 * 64 + (size_t)row * 64 + d4];
        int d = d4 << 2;
        int ph = physrow(row, d);
        As[(d + 0) * 128 + ph] = v.x;
        As[(d + 1) * 128 + ph] = v.y;
        As[(d + 2) * 128 + ph] = v.z;
        As[(d + 3) * 128 + ph] = v.w;
    }
    __syncthreads();

    if (t < 128) {
        #pragma clang fp contract(off)
        float tot = 0.f;
        #pragma unroll
        for (int h = 0; h < 2; ++h) {
            float r[8];
            #pragma unroll
            for (int j = 0; j < 8; ++j) {
                int d = h * 128 + j;
                float a = As[d * 128 + physrow(t, d)];
                float p = a * a;
                r[j] = p;
            }
            for (int i = 1; i < 16; ++i) {
                #pragma unroll
                for (int j = 0; j < 8; ++j) {
                    int d = h * 128 + i * 8 + j;
                    float a = As[d * 128 + physrow(t, d)];
                    float p = a * a;
                    r[j] = r[j] + p;
                }
            }
            float s = ((r[0] + r[1]) + (r[2] + r[3])) + ((r[4] + r[5]) + (r[6] + r[7]));
            tot = tot + s;
        }
        xn[t] = tot;
    }

    float acc[8][8];
    #pragma unroll
    for (int i = 0; i < 8; ++i)
        #pragma unroll
        for (int j = 0; j < 8; ++j) acc[i][j] = 0.f;

    const float4* cbT4 = reinterpret_cast<const float4*>(cbT);

    #pragma unroll 1
    for (int dk = 0; dk < 8; ++dk) {
        __syncthreads();
        #pragma unroll
        for (int it = 0; it < 4; ++it) {
            int fid = it * 256 + t;
            int dd  = fid >> 5;
            int c4  = fid & 31;
            float4 v = cbT4[(size_t)(dk * 32 + dd) * 256 + ct * 32 + c4];
            reinterpret_cast<float4*>(Bs)[dd * 32 + c4] = v;
        }
        __syncthreads();

        #pragma unroll 8
        for (int dd = 0; dd < 32; ++dd) {
            const int d  = dk * 32 + dd;
            const int sw = (dd >> 2) & 7;
            const int ar = ((ty ^ sw) << 2);
            const float4 a0 = *reinterpret_cast<const float4*>(&As[d * 128 + ar]);
            const float4 a1 = *reinterpret_cast<const float4*>(&As[d * 128 + ar + 64]);
            const float4 b0 = *reinterpret_cast<const float4*>(&Bs[dd * 128 + (tx << 2)]);
            const float4 b1 = *reinterpret_cast<const float4*>(&Bs[dd * 128 + (tx << 2) + 64]);
            const float av[8] = {a0.x, a0.y, a0.z, a0.w, a1.x, a1.y, a1.z, a1.w};
            const float bv[8] = {b0.x, b0.y, b0.z, b0.w, b1.x, b1.y, b1.z, b1.w};
            #pragma unroll
            for (int i = 0; i < 8; ++i)
                #pragma unroll
                for (int j = 0; j < 8; ++j)
                    acc[i][j] = fmaf(av[i], bv[j], acc[i][j]);
        }
    }

    u64 emin[8];
    #pragma unroll
    for (int i = 0; i < 8; ++i) emin[i] = ~0ull;
    {
        #pragma clang fp contract(off)
        float cnv[8];
        int   gcl[8];
        #pragma unroll
        for (int j = 0; j < 8; ++j) {
            int cl = (j < 4) ? (tx * 4 + j) : (64 + tx * 4 + (j - 4));
            gcl[j] = ct * 128 + cl;
            cnv[j] = cnorm[gcl[j]];
        }
        #pragma unroll
        for (int i = 0; i < 8; ++i) {
            int rowl = (i < 4) ? (ty * 4 + i) : (64 + ty * 4 + (i - 4));
            float xr = xn[rowl];
            #pragma unroll
            for (int j = 0; j < 8; ++j) {
                float t1 = xr + cnv[j];
                float t2 = 2.0f * acc[i][j];
                float s  = t1 - t2;
                u64 enc = ((u64)__float_as_uint(s) << 32) | (unsigned int)gcl[j];
                if (enc < emin[i]) emin[i] = enc;
            }
        }
    }
    __syncthreads();
    u64* red = reinterpret_cast<u64*>(Bs);   // 128 x 16 u64 = 16 KB
    #pragma unroll
    for (int i = 0; i < 8; ++i) {
        int rowl = (i < 4) ? (ty * 4 + i) : (64 + ty * 4 + (i - 4));
        red[rowl * 16 + tx] = emin[i];
    }
    __syncthreads();
    if (t < 128) {
        u64 m = ~0ull;
        #pragma unroll
        for (int x = 0; x < 16; ++x) m = min(m, red[t * 16 + x]);
        atomicMin(&amin[row0 + t], m);
    }
}

// ---------------------------------------------------------------- fixup ----
__global__ __launch_bounds__(256) void vq_fixup(const int* __restrict__ hardCnt,
                                                const int* __restrict__ hardList,
                                                const u64* __restrict__ amin,
                                                float* __restrict__ counts,
                                                int* __restrict__ idxw,
                                                float* __restrict__ idxf) {
    const int cnt = min(*hardCnt, HCAP);
    int i = blockIdx.x * 256 + threadIdx.x;
    if (i >= cnt) return;
    int tok = hardList[i];
    int code = (int)(amin[i] & 0xFFFFFFFFull);
    idxf[tok] = (float)code;
    idxw[tok] = code;
    unsafeAtomicAdd(&counts[code], 1.0f);
}

// ---------------------------------------------------------------- scan ----
__global__ __launch_bounds__(1024) void vq_scan(const float* __restrict__ counts,
                                                int* __restrict__ offs,
                                                int* __restrict__ cursor) {
    __shared__ int sc[1024];
    const int t = threadIdx.x;
    int c = (int)counts[t];
    sc[t] = c;
    __syncthreads();
    #pragma unroll
    for (int off = 1; off < 1024; off <<= 1) {
        int v = (t >= off) ? sc[t - off] : 0;
        __syncthreads();
        sc[t] += v;
        __syncthreads();
    }
    int excl = sc[t] - c;
    offs[t] = excl;
    cursor[t] = excl;
}

// ------------------------------------------------------------- scatter ----
__global__ __launch_bounds__(256) void vq_scatter(const int* __restrict__ idxw,
                                                  int* __restrict__ cursor,
                                                  int* __restrict__ sorted) {
    int n = blockIdx.x * 256 + threadIdx.x;
    int idx = idxw[n];
    int pos = atomicAdd(&cursor[idx], 1);
    sorted[pos] = n;
}

// ---------------------------------------------------------------- dw ------
__global__ __launch_bounds__(256) void vq_dw(const float* __restrict__ X,
                                             const int* __restrict__ offs,
                                             const float* __restrict__ counts,
                                             const int* __restrict__ sorted,
                                             float* __restrict__ dw) {
    const int k = blockIdx.x;
    const int t = threadIdx.x;
    const int begin = offs[k];
    const int cnt = (int)counts[k];
    const int* seg = sorted + begin;
    float acc = 0.f;
    int i = 0;
    for (; i + 4 <= cnt; i += 4) {
        int t0 = seg[i], t1 = seg[i + 1], t2 = seg[i + 2], t3 = seg[i + 3];
        float a = X[(size_t)t0 * 256 + t];
        float b = X[(size_t)t1 * 256 + t];
        float c = X[(size_t)t2 * 256 + t];
        float d = X[(size_t)t3 * 256 + t];
        acc += a; acc += b; acc += c; acc += d;
    }
    for (; i < cnt; ++i) acc += X[(size_t)seg[i] * 256 + t];
    dw[k * 256 + t] = acc;
}

// ---------------------------------------------------------------- out0 ----
__global__ __launch_bounds__(256) void vq_out0(const float* __restrict__ X,
                                               const float* __restrict__ CB,
                                               const int* __restrict__ idxw,
                                               float* __restrict__ out0,
                                               float* __restrict__ loss) {
    const int t    = threadIdx.x;
    const int wave = (blockIdx.x * 256 + t) >> 6;
    const int lane = t & 63;
    const float4* X4 = reinterpret_cast<const float4*>(X);
    const float4* C4 = reinterpret_cast<const float4*>(CB);
    float4* O4 = reinterpret_cast<float4*>(out0);
    float lsum = 0.f;
    for (int r = 0; r < 64; ++r) {
        const int n = wave * 64 + r;
        const int idx = idxw[n];
        float4 x = X4[n * 64 + lane];
        float4 c = C4[idx * 64 + lane];
        float d0 = c.x - x.x, d1 = c.y - x.y, d2 = c.z - x.z, d3 = c.w - x.w;
        float4 q;
        q.x = x.x + d0; q.y = x.y + d1; q.z = x.z + d2; q.w = x.w + d3;
        O4[n * 64 + lane] = q;
        lsum += d0 * d0 + d1 * d1 + d2 * d2 + d3 * d3;
    }
    #pragma unroll
    for (int off = 32; off; off >>= 1) lsum += __shfl_down(lsum, off, 64);
    if (lane == 0) unsafeAtomicAdd(loss, lsum);
}

// ---------------------------------------------------------- finalize 1 ----
__global__ void vq_fin1(const float* __restrict__ counts,
                        const float* __restrict__ ecs,
                        const float* __restrict__ loss,
                        float* __restrict__ out1, float* __restrict__ out3,
                        float* __restrict__ out4) {
    __shared__ float sd[1024];
    const int t = threadIdx.x;
    float c   = counts[t];
    float pre = 0.99f * ecs[t] + 0.01f * c;
    sd[t] = pre; __syncthreads();
    for (int off = 512; off; off >>= 1) { if (t < off) sd[t] += sd[t + off]; __syncthreads(); }
    float n_total = sd[0];
    __syncthreads();
    float avg = c * (1.0f / 65536.0f);
    float ent = avg * logf(avg + 1e-10f);
    sd[t] = ent; __syncthreads();
    for (int off = 512; off; off >>= 1) { if (t < off) sd[t] += sd[t + off]; __syncthreads(); }
    float entsum = sd[0];
    float ncs = (pre + 1e-5f) / (n_total + 1024.0f * 1e-5f) * n_total;
    out4[t] = ncs;
    if (t == 0) {
        out1[0] = 0.25f * (loss[0] / 16777216.0f);
        out3[0] = expf(-entsum);
    }
}

// ---------------------------------------------------------- finalize 2 ----
__global__ __launch_bounds__(256) void vq_fin2(const float* __restrict__ emw,
                                               const float* __restrict__ dwv,
                                               const float* __restrict__ ncs,
                                               float* __restrict__ out5,
                                               float* __restrict__ out6) {
    int i = blockIdx.x * 256 + threadIdx.x;
    float e = 0.99f * emw[i] + 0.01f * dwv[i];
    out5[i] = e;
    out6[i] = e / ncs[i >> 8];
}

// ---------------------------------------------------------------- launch --
extern "C" void kernel_launch(void* const* d_in, const int* in_sizes, int n_in,
                              void* d_out, int out_size, void* d_ws, size_t ws_size,
                              hipStream_t stream) {
    const float* X   = (const float*)d_in[0];
    const float* CB  = (const float*)d_in[1];
    const float* ECS = (const float*)d_in[2];
    const float* EMW = (const float*)d_in[3];

    float* out0 = (float*)d_out;
    float* out1 = out0 + (size_t)NT * DD;
    float* out2 = out1 + 1;
    float* out3 = out2 + NT;
    float* out4 = out3 + 1;
    float* out5 = out4 + KC;
    float* out6 = out5 + (size_t)KC * DD;

    float* ws       = (float*)d_ws;
    float* counts   = ws + W_COUNTS;
    float* loss     = ws + W_LOSS;
    int*   hardCnt  = (int*)(ws + W_HCNT);
    float* cnorm    = ws + W_CNORM;
    int*   offs     = (int*)(ws + W_OFFS);
    int*   cursor   = (int*)(ws + W_CUR);
    int*   hardList = (int*)(ws + W_HLIST);
    int*   sorted   = (int*)(ws + W_SORT);
    int*   idxw     = (int*)(ws + W_IDX);
    float* dw       = ws + W_DWB;
    u64*   amin     = (u64*)(ws + W_AMIN);
    _Float16* Ccat  = (_Float16*)(ws + W_CCAT);
    float* cbT      = ws + W_CBT;
    float* Xh       = ws + W_XH;

    // Xcat (33.5 MB halves) aliases out0: read by screen, out0 written later.
    _Float16* Xcat = (_Float16*)d_out;

    (void)hipMemsetAsync(ws, 0, 1026 * sizeof(float), stream);
    (void)hipMemsetAsync(amin, 0xFF, (size_t)HCAP * 8, stream);

    vq_prepx<<<NT * DD / 4 / 256, 256, 0, stream>>>(X, Xcat);
    vq_prep<<<KC, 64, 0, stream>>>(CB, Ccat, cnorm, cbT);
    vq_screen<<<NT / 128, 256, 0, stream>>>(Xcat, Ccat, cnorm, counts, idxw, out2,
                                            hardCnt, hardList);
    vq_compact<<<HCAP / 4, 256, 0, stream>>>(X, hardCnt, hardList, Xh);
    vq_exact<<<dim3(HCAP / 128, 8), 256, 36992 * sizeof(float), stream>>>(
        Xh, cbT, cnorm, hardCnt, amin);
    vq_fixup<<<HCAP / 256, 256, 0, stream>>>(hardCnt, hardList, amin, counts,
                                             idxw, out2);
    vq_scan<<<1, 1024, 0, stream>>>(counts, offs, cursor);
    vq_scatter<<<NT / 256, 256, 0, stream>>>(idxw, cursor, sorted);
    vq_dw<<<KC, 256, 0, stream>>>(X, offs, counts, sorted, dw);
    vq_out0<<<256, 256, 0, stream>>>(X, CB, idxw, out0, loss);
    vq_fin1<<<1, 1024, 0, stream>>>(counts, ECS, loss, out1, out3, out4);
    vq_fin2<<<KC * DD / 256, 256, 0, stream>>>(EMW, dw, out4, out5, out6);
}